// Round 12
// baseline (349.189 us; speedup 1.0000x reference)
//
#include <hip/hip_runtime.h>
#include <math.h>

#define NBS 1600      // B*S
#define LL 20
#define EE 300
#define NH 16
#define VD 16
#define HID 256
#define QD 200

typedef short bf16x8 __attribute__((ext_vector_type(8)));
typedef float f32x4 __attribute__((ext_vector_type(4)));

__device__ __forceinline__ short f2b(float f) {
    union { float f; unsigned u; } c; c.f = f;
    unsigned r = (c.u + 0x7FFFu + ((c.u >> 16) & 1u)) >> 16;  // RNE
    return (short)r;
}

__device__ __forceinline__ float ftanh(float a) {
    a = fminf(fmaxf(a, -15.f), 15.f);
    float t = __expf(2.f * a);
    return (t - 1.f) / (t + 1.f);
}

__device__ __forceinline__ void gload16(const short* g, short* l) {
    __builtin_amdgcn_global_load_lds(
        (const __attribute__((address_space(1))) unsigned int*)g,
        (__attribute__((address_space(3))) unsigned int*)l, 16, 0, 0);
}

// ===========================================================================
// Build kernels (linear layouts)
// ===========================================================================

// news/emb -> Xb bf16 [32000][320]; col300 = 1.0 (bias channel), 301..319 = 0
__global__ void build_xb_lin(const int* __restrict__ news, const float* __restrict__ emb,
                             short* __restrict__ Xb) {
    int idx = blockIdx.x * 256 + threadIdx.x;
    if (idx >= 32000 * 80) return;
    int i = idx / 80, e4 = (idx % 80) * 4;
    short4 o;
    if (e4 < 300) {
        const float4 v = *reinterpret_cast<const float4*>(emb + (size_t)news[i] * EE + e4);
        o.x = f2b(v.x); o.y = f2b(v.y); o.z = f2b(v.z); o.w = f2b(v.w);
    } else if (e4 == 300) {
        o.x = (short)0x3F80; o.y = 0; o.z = 0; o.w = 0;
    } else {
        o.x = o.y = o.z = o.w = 0;
    }
    *reinterpret_cast<short4*>(Xb + (size_t)i * 320 + e4) = o;
}

// Wq [n][e][f] -> WqT bf16 [5120 rows = n*320+f][320 cols = e], col300 = qB
__global__ __launch_bounds__(1024) void build_wqt_lin(
    const float* __restrict__ qW, const float* __restrict__ qB, short* __restrict__ WqT)
{
    __shared__ float t[32][33];
    const int n = blockIdx.z;
    const int e0 = blockIdx.x * 32, f0 = blockIdx.y * 32;
    const int tx = threadIdx.x, ty = threadIdx.y;
    const int e = e0 + ty, f = f0 + tx;
    t[ty][tx] = (e < EE && f < EE) ? qW[((size_t)n * EE + e) * EE + f] : 0.f;
    __syncthreads();
    const int fo = f0 + ty, eo = e0 + tx;
    float val;
    if (fo >= EE)      val = 0.f;
    else if (eo < EE)  val = t[tx][ty];
    else if (eo == EE) val = qB[n * EE + fo];
    else               val = 0.f;
    WqT[((size_t)n * 320 + fo) * 320 + eo] = f2b(val);
}

// Wv [n][e][v] -> WvT bf16 [256][320], col300 = vB
__global__ void build_wvt(const float* __restrict__ vW, const float* __restrict__ vB,
                          short* __restrict__ WvT) {
    int idx = blockIdx.x * 256 + threadIdx.x;
    if (idx >= 256 * 320) return;
    int c = idx / 320, e = idx % 320;
    int n = c >> 4, vd = c & 15;
    float val = (e < EE) ? vW[((size_t)n * EE + e) * VD + vd]
                         : (e == EE ? vB[n * VD + vd] : 0.f);
    WvT[idx] = f2b(val);
}

// keyW [200][256] fp32 -> bf16 [208][256]
__global__ void conv_kw(const float* __restrict__ keyW, short* __restrict__ kwb) {
    int idx = blockIdx.x * 256 + threadIdx.x;
    if (idx >= 208 * 256) return;
    int d = idx >> 8;
    kwb[idx] = (d < QD) ? f2b(keyW[idx]) : (short)0;
}

// xv = Xb * WvT^T : [32000][256] bf16.  128x128 tile, 4 waves.
__global__ __launch_bounds__(256) void gemm_xv(
    const short* __restrict__ Xb, const short* __restrict__ WvT, short* __restrict__ xv)
{
    const int nt0 = blockIdx.x * 128;
    const size_t mt0 = (size_t)blockIdx.y * 128;
    const int tid = threadIdx.x, wave = tid >> 6, lane = tid & 63;
    const int lr = lane & 15, lg = lane >> 4;
    const int wm = wave & 1, wn = wave >> 1;

    __shared__ short As[128][68];
    __shared__ short Bs[128][68];
    f32x4 acc[4][4] = {};

    for (int ks = 0; ks < 5; ++ks) {
        __syncthreads();
        for (int u = 0; u < 4; ++u) {
            int idx = u * 256 + tid;
            int rr = idx >> 3, c8 = idx & 7;
            *reinterpret_cast<bf16x8*>(&As[rr][c8 * 8]) =
                *reinterpret_cast<const bf16x8*>(Xb + (mt0 + rr) * 320 + ks * 64 + c8 * 8);
            *reinterpret_cast<bf16x8*>(&Bs[rr][c8 * 8]) =
                *reinterpret_cast<const bf16x8*>(WvT + (size_t)(nt0 + rr) * 320 + ks * 64 + c8 * 8);
        }
        __syncthreads();
        #pragma unroll
        for (int kk = 0; kk < 2; ++kk) {
            bf16x8 af[4], bfv[4];
            #pragma unroll
            for (int f = 0; f < 4; ++f)
                af[f] = *reinterpret_cast<const bf16x8*>(&As[wm * 64 + f * 16 + lr][kk * 32 + lg * 8]);
            #pragma unroll
            for (int f = 0; f < 4; ++f)
                bfv[f] = *reinterpret_cast<const bf16x8*>(&Bs[wn * 64 + f * 16 + lr][kk * 32 + lg * 8]);
            #pragma unroll
            for (int i = 0; i < 4; ++i)
                #pragma unroll
                for (int j = 0; j < 4; ++j)
                    acc[i][j] = __builtin_amdgcn_mfma_f32_16x16x32_bf16(af[i], bfv[j], acc[i][j], 0, 0, 0);
        }
    }
    #pragma unroll
    for (int i = 0; i < 4; ++i)
        #pragma unroll
        for (int j = 0; j < 4; ++j)
            #pragma unroll
            for (int r = 0; r < 4; ++r)
                xv[(mt0 + wm * 64 + i * 16 + lg * 4 + r) * 256 + nt0 + wn * 64 + j * 16 + lr]
                    = f2b(acc[i][j][r]);
}

// ---------------------------------------------------------------------------
// gemm_q: m97-exact GEMM slab.  C[slabRows][5120] = Xb[slab] * WqT^T.
// 128x128 tile, 4 waves (64x64 each, 4x4 frags), BK=32, global_load_lds(16B),
// linear LDS A[128][32]+B[128][32] = 16 KB -> 4+ blocks/CU.
// ---------------------------------------------------------------------------
__global__ __launch_bounds__(256, 4) void gemm_q(
    const short* __restrict__ Xb,    // [32000][320]
    const short* __restrict__ WqT,   // [5120][320]
    short*       __restrict__ q,     // [slabRows][5120]
    int rowbase)
{
    const int nt0 = blockIdx.x * 128;
    const int mt0 = blockIdx.y * 128;
    const int tid = threadIdx.x, wave = tid >> 6, lane = tid & 63;
    const int lr = lane & 15, lg = lane >> 4;
    const int wm = wave & 1, wn = wave >> 1;

    __shared__ short sAB[8192];      // A @ [0,4096) shorts, B @ [4096,8192)

    const int rA = tid >> 2, c = tid & 3;   // seg: 4 segs of 16B per 32-col row
    const short* aS0 = Xb + (size_t)(rowbase + mt0 + rA) * 320 + c * 8;
    const short* aS1 = aS0 + (size_t)64 * 320;
    const short* bS0 = WqT + (size_t)(nt0 + rA) * 320 + c * 8;
    const short* bS1 = bS0 + (size_t)64 * 320;
    short* d0 = sAB + tid * 8;              // linear lane-contiguous glds dests
    short* d1 = sAB + (tid + 256) * 8;
    short* d2 = sAB + (tid + 512) * 8;
    short* d3 = sAB + (tid + 768) * 8;

    f32x4 acc[4][4] = {};
    for (int ks = 0; ks < 10; ++ks) {
        __syncthreads();                    // previous step's frag reads done
        const int ko = ks * 32;
        gload16(aS0 + ko, d0);
        gload16(aS1 + ko, d1);
        gload16(bS0 + ko, d2);
        gload16(bS1 + ko, d3);
        __syncthreads();                    // glds drained (vmcnt 0 at barrier)
        bf16x8 af[4], bfr[4];
        #pragma unroll
        for (int i = 0; i < 4; ++i)
            af[i] = *reinterpret_cast<const bf16x8*>(sAB + (wm * 64 + i * 16 + lr) * 32 + lg * 8);
        #pragma unroll
        for (int j = 0; j < 4; ++j)
            bfr[j] = *reinterpret_cast<const bf16x8*>(sAB + 4096 + (wn * 64 + j * 16 + lr) * 32 + lg * 8);
        #pragma unroll
        for (int i = 0; i < 4; ++i)
            #pragma unroll
            for (int j = 0; j < 4; ++j)
                acc[i][j] = __builtin_amdgcn_mfma_f32_16x16x32_bf16(af[i], bfr[j], acc[i][j], 0, 0, 0);
    }

    #pragma unroll
    for (int i = 0; i < 4; ++i)
        #pragma unroll
        for (int j = 0; j < 4; ++j)
            #pragma unroll
            for (int r = 0; r < 4; ++r)
                q[(size_t)(mt0 + wm * 64 + i * 16 + lg * 4 + r) * 5120
                  + nt0 + wn * 64 + j * 16 + lr] = f2b(acc[i][j][r]);
}

// ---------------------------------------------------------------------------
// sv: scores + softmax + v per slab.  grid = bscount*4 blocks, 256 thr,
// one head per wave (4 heads/block).  q from L3, x staged in LDS,
// no inner barriers (atw is wave-private).
// ---------------------------------------------------------------------------
__global__ __launch_bounds__(256, 3) void sv(
    const short* __restrict__ Xb,    // [32000][320]
    const short* __restrict__ q,     // [slabRows][5120]
    const short* __restrict__ xv,    // [32000][256]
    float*       __restrict__ out1,  // [32000][256]
    int bsbase)
{
    const int bs = bsbase + (blockIdx.x >> 2);
    const int hq = blockIdx.x & 3;
    const int tid = threadIdx.x, wave = tid >> 6, lane = tid & 63;
    const int lr = lane & 15, lg = lane >> 4;
    const int n = hq * 4 + wave;

    __shared__ short xs[20][328];        // stride 164 dw == 4 mod 32
    __shared__ short atw[4][32][34];     // per-wave attn scratch

    for (int i = tid; i < 2176; i += 256) reinterpret_cast<int*>(atw)[i] = 0;
    for (int idx = tid; idx < 800; idx += 256) {
        int l = idx / 40, c8 = idx % 40;
        *reinterpret_cast<bf16x8*>(&xs[l][c8 * 8]) =
            *reinterpret_cast<const bf16x8*>(Xb + ((size_t)bs * 20 + l) * 320 + c8 * 8);
    }
    __syncthreads();

    const short* qb = q + (size_t)(bs - bsbase) * 20 * 5120 + n * 320;
    int l1 = 16 + lr; if (l1 > 19) l1 = 19;

    f32x4 s[2][2] = {};
    #pragma unroll
    for (int ks = 0; ks < 10; ++ks) {
        const int ko = ks * 32 + lg * 8;
        bf16x8 a0 = *reinterpret_cast<const bf16x8*>(qb + (size_t)lr * 5120 + ko);
        bf16x8 a1 = *reinterpret_cast<const bf16x8*>(qb + (size_t)l1 * 5120 + ko);
        bf16x8 b0 = *reinterpret_cast<const bf16x8*>(&xs[lr][ko]);
        bf16x8 b1 = *reinterpret_cast<const bf16x8*>(&xs[l1][ko]);
        s[0][0] = __builtin_amdgcn_mfma_f32_16x16x32_bf16(a0, b0, s[0][0], 0, 0, 0);
        s[0][1] = __builtin_amdgcn_mfma_f32_16x16x32_bf16(a0, b1, s[0][1], 0, 0, 0);
        s[1][0] = __builtin_amdgcn_mfma_f32_16x16x32_bf16(a1, b0, s[1][0], 0, 0, 0);
        s[1][1] = __builtin_amdgcn_mfma_f32_16x16x32_bf16(a1, b1, s[1][1], 0, 0, 0);
    }

    const float scl = 0.057735026918962584f;  // 1/sqrt(300)
    #pragma unroll
    for (int mts = 0; mts < 2; ++mts) {
        #pragma unroll
        for (int r = 0; r < 4; ++r) {
            float v0 = s[mts][0][r] * scl;
            float v1 = s[mts][1][r] * scl;
            float mx = (lr < 4) ? fmaxf(v0, v1) : v0;
            mx = fmaxf(mx, __shfl_xor(mx, 1));
            mx = fmaxf(mx, __shfl_xor(mx, 2));
            mx = fmaxf(mx, __shfl_xor(mx, 4));
            mx = fmaxf(mx, __shfl_xor(mx, 8));
            float e0 = __expf(v0 - mx);
            float e1 = (lr < 4) ? __expf(v1 - mx) : 0.f;
            float sm = e0 + e1;
            sm += __shfl_xor(sm, 1);
            sm += __shfl_xor(sm, 2);
            sm += __shfl_xor(sm, 4);
            sm += __shfl_xor(sm, 8);
            const float inv = 1.f / sm;
            const int row = mts * 16 + lg * 4 + r;
            if (row < LL) {
                atw[wave][row][lr]      = f2b(e0 * inv);
                atw[wave][row][16 + lr] = f2b(e1 * inv);   // lr>=4 writes 0
            }
        }
    }
    // wave-private atw: ds-write -> ds-read ordering handled by lgkmcnt

    bf16x8 bv;
    #pragma unroll
    for (int j = 0; j < 8; ++j) {
        int m = lg * 8 + j; if (m > 19) m = 19;   // attn cols >=20 are zero
        bv[j] = xv[((size_t)bs * 20 + m) * 256 + n * 16 + lr];
    }
    bf16x8 va0 = *reinterpret_cast<const bf16x8*>(&atw[wave][lr][lg * 8]);
    bf16x8 va1 = *reinterpret_cast<const bf16x8*>(&atw[wave][16 + lr][lg * 8]);
    f32x4 z = {0.f, 0.f, 0.f, 0.f};
    f32x4 v0 = __builtin_amdgcn_mfma_f32_16x16x32_bf16(va0, bv, z, 0, 0, 0);
    f32x4 v1 = __builtin_amdgcn_mfma_f32_16x16x32_bf16(va1, bv, z, 0, 0, 0);
    #pragma unroll
    for (int r = 0; r < 4; ++r) {
        const int rowl = lg * 4 + r;
        out1[((size_t)bs * 20 + rowl) * 256 + n * 16 + lr] = v0[r];
        const int rowl1 = 16 + lg * 4 + r;
        if (rowl1 < LL)
            out1[((size_t)bs * 20 + rowl1) * 256 + n * 16 + lr] = v1[r];
    }
}

// ---------------------------------------------------------------------------
// Pool (proven)
// ---------------------------------------------------------------------------
__global__ __launch_bounds__(256) void nrms_pool_mfma(
    const float* __restrict__ out1,
    const short* __restrict__ kwb,
    const float* __restrict__ keyB,
    const float* __restrict__ query,
    float*       __restrict__ out2)
{
    const int bs   = blockIdx.x;
    const int tid  = threadIdx.x;
    const int wave = tid >> 6;
    const int lane = tid & 63;
    const int lr   = lane & 15;
    const int lg   = lane >> 4;

    __shared__ float mh[LL][257];
    __shared__ short mhb[32][264];
    __shared__ float s2p[32];

    for (int i = tid; i < 12 * 128; i += 256) {
        const int r = 20 + i / 128, c = (i % 128) * 2;
        *reinterpret_cast<int*>(&mhb[r][c]) = 0;
    }
    if (tid < 32) s2p[tid] = 0.f;

    for (int idx = tid; idx < LL * 64; idx += 256) {
        const int l = idx >> 6, h4 = (idx & 63) * 4;
        const float4 v = *reinterpret_cast<const float4*>(out1 + ((size_t)bs * LL + l) * HID + h4);
        mh[l][h4] = v.x; mh[l][h4 + 1] = v.y; mh[l][h4 + 2] = v.z; mh[l][h4 + 3] = v.w;
        mhb[l][h4] = f2b(v.x); mhb[l][h4 + 1] = f2b(v.y);
        mhb[l][h4 + 2] = f2b(v.z); mhb[l][h4 + 3] = f2b(v.w);
    }
    __syncthreads();

    for (int t = wave; t < 26; t += 4) {
        const int mt = t & 1, nt = t >> 1;
        f32x4 acc = {0.f, 0.f, 0.f, 0.f};
        const short* ap = &mhb[mt * 16 + lr][lg * 8];
        const short* bp = kwb + (nt * 16 + lr) * 256 + lg * 8;
        #pragma unroll
        for (int k = 0; k < 8; ++k) {
            bf16x8 a = *reinterpret_cast<const bf16x8*>(ap + k * 32);
            bf16x8 b = *reinterpret_cast<const bf16x8*>(bp + k * 32);
            acc = __builtin_amdgcn_mfma_f32_16x16x32_bf16(a, b, acc, 0, 0, 0);
        }
        const int d = nt * 16 + lr;
        const float qd = (d < QD) ? query[d] : 0.f;
        const float kb = (d < QD) ? keyB[d] : 0.f;
        float vals[4];
        #pragma unroll
        for (int r = 0; r < 4; ++r) vals[r] = qd * ftanh(acc[r] + kb);
        #pragma unroll
        for (int off = 1; off < 16; off <<= 1) {
            #pragma unroll
            for (int r = 0; r < 4; ++r) vals[r] += __shfl_xor(vals[r], off);
        }
        if (lr == 0) {
            #pragma unroll
            for (int r = 0; r < 4; ++r)
                atomicAdd(&s2p[mt * 16 + lg * 4 + r], vals[r]);
        }
    }
    __syncthreads();

    if (tid == 0) {
        float mx = -1e30f;
        #pragma unroll
        for (int l = 0; l < LL; ++l) mx = fmaxf(mx, s2p[l] * 0.07071067811865475f);
        float sum = 0.f;
        float e[LL];
        #pragma unroll
        for (int l = 0; l < LL; ++l) { e[l] = __expf(s2p[l] * 0.07071067811865475f - mx); sum += e[l]; }
        const float inv = 1.f / sum;
        #pragma unroll
        for (int l = 0; l < LL; ++l) s2p[l] = e[l] * inv;
    }
    __syncthreads();

    {
        const int h = tid;
        float acc = 0.f;
        #pragma unroll
        for (int l = 0; l < LL; ++l) acc = fmaf(s2p[l], mh[l][h], acc);
        out2[(size_t)bs * HID + h] = acc;
    }
}

// ===========================================================================
// FALLBACK (round-3, 3.4 MB ws)
// ===========================================================================

#define XP 330
#define TP 42
#define AP 34

__global__ __launch_bounds__(1024) void transpose_qw(
    const float* __restrict__ qW, short* __restrict__ wqt)
{
    __shared__ float t[32][33];
    const int n = blockIdx.z;
    const int e0 = blockIdx.x * 32, f0 = blockIdx.y * 32;
    const int tx = threadIdx.x, ty = threadIdx.y;
    const int e = e0 + ty, f = f0 + tx;
    t[ty][tx] = (e < EE && f < EE) ? qW[(size_t)n * EE * EE + e * EE + f] : 0.f;
    __syncthreads();
    const int fo = f0 + ty, eo = e0 + tx;
    if (fo < 304)
        wqt[(size_t)n * 304 * 320 + fo * 320 + eo] = f2b(t[tx][ty]);
}

__global__ void conv_vw(const float* __restrict__ vW, short* __restrict__ wvt) {
    int idx = blockIdx.x * 256 + threadIdx.x;
    if (idx >= NH * VD * 320) return;
    int e = idx % 320;
    int v = (idx / 320) % VD;
    int n = idx / (320 * VD);
    wvt[idx] = (e < EE) ? f2b(vW[(size_t)n * EE * VD + e * VD + v]) : (short)0;
}

__global__ __launch_bounds__(512) void nrms_attn_mfma(
    const int*   __restrict__ news,
    const float* __restrict__ emb,
    const short* __restrict__ wqt,
    const float* __restrict__ qB,
    const short* __restrict__ wvt,
    const float* __restrict__ vB,
    float*       __restrict__ out1)
{
    const int bs   = blockIdx.x;
    const int tid  = threadIdx.x;
    const int wave = tid >> 6;
    const int lane = tid & 63;
    const int lr   = lane & 15;
    const int lg   = lane >> 4;

    __shared__ short xs[32][XP];
    __shared__ short xT[320][TP];
    __shared__ short qs[32][XP];
    __shared__ float sc[32][33];
    __shared__ short at[32][AP];

    {
        int* z = (int*)&xs[0][0];
        for (int i = tid; i < 32 * XP / 2; i += 512) z[i] = 0;
        z = (int*)&qs[0][0];
        for (int i = tid; i < 32 * XP / 2; i += 512) z[i] = 0;
        z = (int*)&xT[0][0];
        for (int i = tid; i < 320 * TP / 2; i += 512) z[i] = 0;
    }
    __syncthreads();

    for (int idx = tid; idx < LL * 75; idx += 512) {
        const int l = idx / 75, e4 = (idx % 75) * 4;
        const int row = news[bs * LL + l];
        const float4 v = *reinterpret_cast<const float4*>(emb + (size_t)row * EE + e4);
        const short b0 = f2b(v.x), b1 = f2b(v.y), b2 = f2b(v.z), b3 = f2b(v.w);
        xs[l][e4] = b0; xs[l][e4 + 1] = b1; xs[l][e4 + 2] = b2; xs[l][e4 + 3] = b3;
        xT[e4][l] = b0; xT[e4 + 1][l] = b1; xT[e4 + 2][l] = b2; xT[e4 + 3][l] = b3;
    }
    __syncthreads();

    for (int n = 0; n < NH; ++n) {
        const short* wq = wqt + (size_t)n * 304 * 320;

        for (int p = wave; p < 19; p += 8) {
            f32x4 acc0 = {0.f, 0.f, 0.f, 0.f};
            f32x4 acc1 = {0.f, 0.f, 0.f, 0.f};
            const short* a0p = &xs[lr][lg * 8];
            const short* a1p = &xs[16 + lr][lg * 8];
            const short* bp  = wq + (p * 16 + lr) * 320 + lg * 8;
            #pragma unroll
            for (int k = 0; k < 10; ++k) {
                bf16x8 b  = *reinterpret_cast<const bf16x8*>(bp + k * 32);
                bf16x8 a0 = *reinterpret_cast<const bf16x8*>(a0p + k * 32);
                bf16x8 a1 = *reinterpret_cast<const bf16x8*>(a1p + k * 32);
                acc0 = __builtin_amdgcn_mfma_f32_16x16x32_bf16(a0, b, acc0, 0, 0, 0);
                acc1 = __builtin_amdgcn_mfma_f32_16x16x32_bf16(a1, b, acc1, 0, 0, 0);
            }
            const int col = p * 16 + lr;
            const float bias = (col < EE) ? qB[n * EE + col] : 0.f;
            #pragma unroll
            for (int r = 0; r < 4; ++r) {
                qs[lg * 4 + r][col]      = f2b(acc0[r] + bias);
                qs[16 + lg * 4 + r][col] = f2b(acc1[r] + bias);
            }
        }
        __syncthreads();

        if (wave < 4) {
            const int mt = wave & 1, nt = wave >> 1;
            f32x4 acc = {0.f, 0.f, 0.f, 0.f};
            const short* ap = &qs[mt * 16 + lr][lg * 8];
            const short* bp = &xs[nt * 16 + lr][lg * 8];
            #pragma unroll
            for (int k = 0; k < 10; ++k) {
                bf16x8 a = *reinterpret_cast<const bf16x8*>(ap + k * 32);
                bf16x8 b = *reinterpret_cast<const bf16x8*>(bp + k * 32);
                acc = __builtin_amdgcn_mfma_f32_16x16x32_bf16(a, b, acc, 0, 0, 0);
            }
            #pragma unroll
            for (int r = 0; r < 4; ++r)
                sc[mt * 16 + lg * 4 + r][nt * 16 + lr] = acc[r] * 0.057735026918962584f;
        }
        __syncthreads();

        if (tid < LL) {
            float mx = -1e30f;
            #pragma unroll
            for (int m = 0; m < LL; ++m) mx = fmaxf(mx, sc[tid][m]);
            float ev[LL], sum = 0.f;
            #pragma unroll
            for (int m = 0; m < LL; ++m) { ev[m] = __expf(sc[tid][m] - mx); sum += ev[m]; }
            const float inv = 1.f / sum;
            #pragma unroll
            for (int m = 0; m < LL; ++m) at[tid][m] = f2b(ev[m] * inv);
            #pragma unroll
            for (int m = LL; m < 32; ++m) at[tid][m] = 0;
        } else if (tid < 32) {
            int* zr = (int*)&at[tid][0];
            #pragma unroll
            for (int m = 0; m < 16; ++m) zr[m] = 0;
        }
        __syncthreads();

        for (int p = wave; p < 19; p += 8) {
            bf16x8 b  = *reinterpret_cast<const bf16x8*>(&xT[p * 16 + lr][lg * 8]);
            bf16x8 a0 = *reinterpret_cast<const bf16x8*>(&at[lr][lg * 8]);
            bf16x8 a1 = *reinterpret_cast<const bf16x8*>(&at[16 + lr][lg * 8]);
            f32x4 z = {0.f, 0.f, 0.f, 0.f};
            f32x4 c0 = __builtin_amdgcn_mfma_f32_16x16x32_bf16(a0, b, z, 0, 0, 0);
            f32x4 c1 = __builtin_amdgcn_mfma_f32_16x16x32_bf16(a1, b, z, 0, 0, 0);
            const int col = p * 16 + lr;
            #pragma unroll
            for (int r = 0; r < 4; ++r) {
                qs[lg * 4 + r][col]      = f2b(c0[r]);
                qs[16 + lg * 4 + r][col] = f2b(c1[r]);
            }
        }
        __syncthreads();

        if (wave < 2) {
            const int mt = wave;
            f32x4 acc = {0.f, 0.f, 0.f, 0.f};
            const short* ap = &qs[mt * 16 + lr][lg * 8];
            const short* bp = wvt + (size_t)n * VD * 320 + lr * 320 + lg * 8;
            #pragma unroll
            for (int k = 0; k < 10; ++k) {
                bf16x8 a = *reinterpret_cast<const bf16x8*>(ap + k * 32);
                bf16x8 b = *reinterpret_cast<const bf16x8*>(bp + k * 32);
                acc = __builtin_amdgcn_mfma_f32_16x16x32_bf16(a, b, acc, 0, 0, 0);
            }
            #pragma unroll
            for (int r = 0; r < 4; ++r) {
                const int row = mt * 16 + lg * 4 + r;
                if (row < LL)
                    out1[((size_t)bs * LL + row) * HID + n * VD + lr] = acc[r] + vB[n * VD + lr];
            }
        }
        __syncthreads();
    }
}

// ===========================================================================

extern "C" void kernel_launch(void* const* d_in, const int* in_sizes, int n_in,
                              void* d_out, int out_size, void* d_ws, size_t ws_size,
                              hipStream_t stream) {
    const int*   news  = (const int*)d_in[0];
    const float* emb   = (const float*)d_in[1];
    const float* qW    = (const float*)d_in[2];
    const float* qB    = (const float*)d_in[3];
    const float* vW    = (const float*)d_in[4];
    const float* vB    = (const float*)d_in[5];
    const float* keyW  = (const float*)d_in[6];
    const float* keyB  = (const float*)d_in[7];
    const float* query = (const float*)d_in[8];

    float* out1 = (float*)d_out;            // news_embedding: 8192000 floats
    float* out2 = out1 + 8192000;           // news_repr: 409600 floats

    // base buffers (shorts): Xb 10.24M, WqT 1.6384M, WvT 81920, xv 8.192M, kwb 53248
    const size_t BASE_SH = 10240000ull + 1638400 + 81920 + 8192000 + 53248;
    const size_t BASE_B  = BASE_SH * 2;                 // 40.4 MB
    const size_t UNIT_B  = 640ull * 5120 * 2;           // 6.55 MB per 640-row q unit

    size_t ucap = (ws_size > BASE_B) ? (ws_size - BASE_B) / UNIT_B : 0;
    // Cap slab at u=10 (65.5 MB): fits the 256 MB Infinity Cache so the q
    // intermediate never round-trips HBM (write absorbed, sv reads hit L3).
    int u = (int)((ucap > 10) ? 10 : ucap);

    if (u >= 1) {
        short* Xb  = (short*)d_ws;
        short* WqT = Xb + 10240000;
        short* WvT = WqT + 1638400;
        short* xv  = WvT + 81920;
        short* kwb = xv + 8192000;
        short* qb  = kwb + 53248;                       // slab q buffer (reused)

        hipLaunchKernelGGL(build_xb_lin, dim3(10000), dim3(256), 0, stream, news, emb, Xb);
        hipLaunchKernelGGL(build_wqt_lin, dim3(10, 10, 16), dim3(32, 32), 0, stream, qW, qB, WqT);
        hipLaunchKernelGGL(build_wvt, dim3(320), dim3(256), 0, stream, vW, vB, WvT);
        hipLaunchKernelGGL(conv_kw, dim3(208), dim3(256), 0, stream, keyW, kwb);
        hipLaunchKernelGGL(gemm_xv, dim3(2, 250), dim3(256), 0, stream, Xb, WvT, xv);

        for (int r0 = 0; r0 < 50; r0 += u) {            // 50 units of 640 rows
            const int uu = (u < 50 - r0) ? u : (50 - r0);
            hipLaunchKernelGGL(gemm_q, dim3(40, uu * 5), dim3(256), 0, stream,
                               Xb, WqT, qb, r0 * 640);
            hipLaunchKernelGGL(sv, dim3(uu * 128), dim3(256), 0, stream,
                               Xb, qb, xv, out1, r0 * 32);
        }
        hipLaunchKernelGGL(nrms_pool_mfma, dim3(NBS), dim3(256), 0, stream,
                           out1, kwb, keyB, query, out2);
    } else {
        short* wqt = (short*)d_ws;
        short* wvt = wqt + (size_t)NH * 304 * 320;
        short* kwb = wvt + (size_t)NH * VD * 320;

        hipLaunchKernelGGL(transpose_qw, dim3(10, 10, 16), dim3(32, 32), 0, stream, qW, wqt);
        hipLaunchKernelGGL(conv_vw, dim3(320), dim3(256), 0, stream, vW, wvt);
        hipLaunchKernelGGL(conv_kw, dim3(208), dim3(256), 0, stream, keyW, kwb);
        hipLaunchKernelGGL(nrms_attn_mfma, dim3(NBS), dim3(512), 0, stream,
                           news, emb, wqt, qB, wvt, vB, out1);
        hipLaunchKernelGGL(nrms_pool_mfma, dim3(NBS), dim3(256), 0, stream,
                           out1, kwb, keyB, query, out2);
    }
}

// Round 13
// 327.095 us; speedup vs baseline: 1.0675x; 1.0675x over previous
//
#include <hip/hip_runtime.h>
#include <math.h>

#define NBS 1600      // B*S
#define LL 20
#define EE 300
#define NH 16
#define VD 16
#define HID 256
#define QD 200

typedef short bf16x8 __attribute__((ext_vector_type(8)));
typedef float f32x4 __attribute__((ext_vector_type(4)));

__device__ __forceinline__ short f2b(float f) {
    union { float f; unsigned u; } c; c.f = f;
    unsigned r = (c.u + 0x7FFFu + ((c.u >> 16) & 1u)) >> 16;  // RNE
    return (short)r;
}

__device__ __forceinline__ float b2f(short s) {
    union { unsigned u; float f; } c; c.u = ((unsigned)(unsigned short)s) << 16;
    return c.f;
}

__device__ __forceinline__ float ftanh(float a) {
    a = fminf(fmaxf(a, -15.f), 15.f);
    float t = __expf(2.f * a);
    return (t - 1.f) / (t + 1.f);
}

__device__ __forceinline__ void gload16(const short* g, short* l) {
    __builtin_amdgcn_global_load_lds(
        (const __attribute__((address_space(1))) unsigned int*)g,
        (__attribute__((address_space(3))) unsigned int*)l, 16, 0, 0);
}

// ===========================================================================
// Build kernels
// ===========================================================================

// news/emb -> Xb bf16 [32000][320]; col300 = 1.0 (bias channel), 301..319 = 0
__global__ void build_xb_lin(const int* __restrict__ news, const float* __restrict__ emb,
                             short* __restrict__ Xb) {
    int idx = blockIdx.x * 256 + threadIdx.x;
    if (idx >= 32000 * 80) return;
    int i = idx / 80, e4 = (idx % 80) * 4;
    short4 o;
    if (e4 < 300) {
        const float4 v = *reinterpret_cast<const float4*>(emb + (size_t)news[i] * EE + e4);
        o.x = f2b(v.x); o.y = f2b(v.y); o.z = f2b(v.z); o.w = f2b(v.w);
    } else if (e4 == 300) {
        o.x = (short)0x3F80; o.y = 0; o.z = 0; o.w = 0;
    } else {
        o.x = o.y = o.z = o.w = 0;
    }
    *reinterpret_cast<short4*>(Xb + (size_t)i * 320 + e4) = o;
}

// Wq [n][e][f] -> WqT bf16 [5120 rows = n*320+f][320 cols = e], col300 = qB
__global__ __launch_bounds__(1024) void build_wqt_lin(
    const float* __restrict__ qW, const float* __restrict__ qB, short* __restrict__ WqT)
{
    __shared__ float t[32][33];
    const int n = blockIdx.z;
    const int e0 = blockIdx.x * 32, f0 = blockIdx.y * 32;
    const int tx = threadIdx.x, ty = threadIdx.y;
    const int e = e0 + ty, f = f0 + tx;
    t[ty][tx] = (e < EE && f < EE) ? qW[((size_t)n * EE + e) * EE + f] : 0.f;
    __syncthreads();
    const int fo = f0 + ty, eo = e0 + tx;
    float val;
    if (fo >= EE)      val = 0.f;
    else if (eo < EE)  val = t[tx][ty];
    else if (eo == EE) val = qB[n * EE + fo];
    else               val = 0.f;
    WqT[((size_t)n * 320 + fo) * 320 + eo] = f2b(val);
}

// Wv [n][e][v] -> WvT bf16 [256][320], col300 = vB
__global__ void build_wvt(const float* __restrict__ vW, const float* __restrict__ vB,
                          short* __restrict__ WvT) {
    int idx = blockIdx.x * 256 + threadIdx.x;
    if (idx >= 256 * 320) return;
    int c = idx / 320, e = idx % 320;
    int n = c >> 4, vd = c & 15;
    float val = (e < EE) ? vW[((size_t)n * EE + e) * VD + vd]
                         : (e == EE ? vB[n * VD + vd] : 0.f);
    WvT[idx] = f2b(val);
}

// keyW [200][256] fp32 -> bf16 kwb2 [256][256] (rows >=200 zero)
__global__ void conv_kw(const float* __restrict__ keyW, short* __restrict__ kwb) {
    int idx = blockIdx.x * 256 + threadIdx.x;
    if (idx >= 256 * 256) return;
    int d = idx >> 8;
    kwb[idx] = (d < QD) ? f2b(keyW[idx]) : (short)0;
}

// xv = Xb * WvT^T : [32000][256] bf16.  128x128 tile, 4 waves.
__global__ __launch_bounds__(256) void gemm_xv(
    const short* __restrict__ Xb, const short* __restrict__ WvT, short* __restrict__ xv)
{
    const int nt0 = blockIdx.x * 128;
    const size_t mt0 = (size_t)blockIdx.y * 128;
    const int tid = threadIdx.x, wave = tid >> 6, lane = tid & 63;
    const int lr = lane & 15, lg = lane >> 4;
    const int wm = wave & 1, wn = wave >> 1;

    __shared__ short As[128][68];
    __shared__ short Bs[128][68];
    f32x4 acc[4][4] = {};

    for (int ks = 0; ks < 5; ++ks) {
        __syncthreads();
        for (int u = 0; u < 4; ++u) {
            int idx = u * 256 + tid;
            int rr = idx >> 3, c8 = idx & 7;
            *reinterpret_cast<bf16x8*>(&As[rr][c8 * 8]) =
                *reinterpret_cast<const bf16x8*>(Xb + (mt0 + rr) * 320 + ks * 64 + c8 * 8);
            *reinterpret_cast<bf16x8*>(&Bs[rr][c8 * 8]) =
                *reinterpret_cast<const bf16x8*>(WvT + (size_t)(nt0 + rr) * 320 + ks * 64 + c8 * 8);
        }
        __syncthreads();
        #pragma unroll
        for (int kk = 0; kk < 2; ++kk) {
            bf16x8 af[4], bfv[4];
            #pragma unroll
            for (int f = 0; f < 4; ++f)
                af[f] = *reinterpret_cast<const bf16x8*>(&As[wm * 64 + f * 16 + lr][kk * 32 + lg * 8]);
            #pragma unroll
            for (int f = 0; f < 4; ++f)
                bfv[f] = *reinterpret_cast<const bf16x8*>(&Bs[wn * 64 + f * 16 + lr][kk * 32 + lg * 8]);
            #pragma unroll
            for (int i = 0; i < 4; ++i)
                #pragma unroll
                for (int j = 0; j < 4; ++j)
                    acc[i][j] = __builtin_amdgcn_mfma_f32_16x16x32_bf16(af[i], bfv[j], acc[i][j], 0, 0, 0);
        }
    }
    #pragma unroll
    for (int i = 0; i < 4; ++i)
        #pragma unroll
        for (int j = 0; j < 4; ++j)
            #pragma unroll
            for (int r = 0; r < 4; ++r)
                xv[(mt0 + wm * 64 + i * 16 + lg * 4 + r) * 256 + nt0 + wn * 64 + j * 16 + lr]
                    = f2b(acc[i][j][r]);
}

// ---------------------------------------------------------------------------
// gemm_q: m97-exact slab GEMM, output in head-major q2 layout
// q2[bs_local][n][l][320].  128x128 tile, BK=32, glds(16B), 16 KB LDS.
// ---------------------------------------------------------------------------
__global__ __launch_bounds__(256, 4) void gemm_q(
    const short* __restrict__ Xb,    // [32000][320]
    const short* __restrict__ WqT,   // [5120][320]
    short*       __restrict__ q2,    // [slabBs][16][20][320]
    int rowbase)
{
    const int nt0 = blockIdx.x * 128;
    const int mt0 = blockIdx.y * 128;
    const int tid = threadIdx.x, wave = tid >> 6, lane = tid & 63;
    const int lr = lane & 15, lg = lane >> 4;
    const int wm = wave & 1, wn = wave >> 1;

    __shared__ short sAB[8192];      // A @ [0,4096) shorts, B @ [4096,8192)

    const int rA = tid >> 2, c = tid & 3;
    const short* aS0 = Xb + (size_t)(rowbase + mt0 + rA) * 320 + c * 8;
    const short* aS1 = aS0 + (size_t)64 * 320;
    const short* bS0 = WqT + (size_t)(nt0 + rA) * 320 + c * 8;
    const short* bS1 = bS0 + (size_t)64 * 320;
    short* d0 = sAB + tid * 8;
    short* d1 = sAB + (tid + 256) * 8;
    short* d2 = sAB + (tid + 512) * 8;
    short* d3 = sAB + (tid + 768) * 8;

    f32x4 acc[4][4] = {};
    for (int ks = 0; ks < 10; ++ks) {
        __syncthreads();
        const int ko = ks * 32;
        gload16(aS0 + ko, d0);
        gload16(aS1 + ko, d1);
        gload16(bS0 + ko, d2);
        gload16(bS1 + ko, d3);
        __syncthreads();
        bf16x8 af[4], bfr[4];
        #pragma unroll
        for (int i = 0; i < 4; ++i)
            af[i] = *reinterpret_cast<const bf16x8*>(sAB + (wm * 64 + i * 16 + lr) * 32 + lg * 8);
        #pragma unroll
        for (int j = 0; j < 4; ++j)
            bfr[j] = *reinterpret_cast<const bf16x8*>(sAB + 4096 + (wn * 64 + j * 16 + lr) * 32 + lg * 8);
        #pragma unroll
        for (int i = 0; i < 4; ++i)
            #pragma unroll
            for (int j = 0; j < 4; ++j)
                acc[i][j] = __builtin_amdgcn_mfma_f32_16x16x32_bf16(af[i], bfr[j], acc[i][j], 0, 0, 0);
    }

    // epilogue: head-major q2 write.  Each 16-col group lies in one head.
    #pragma unroll
    for (int j = 0; j < 4; ++j) {
        const int colbase = nt0 + wn * 64 + j * 16;
        const int n = colbase / 320;
        const int f = colbase - n * 320 + lr;
        #pragma unroll
        for (int i = 0; i < 4; ++i)
            #pragma unroll
            for (int r = 0; r < 4; ++r) {
                const int ml = mt0 + wm * 64 + i * 16 + lg * 4 + r;   // slab-local row
                const int bsl = ml / 20;
                const int l = ml - bsl * 20;
                q2[((size_t)(bsl * 16 + n) * 20 + l) * 320 + f] = f2b(acc[i][j][r]);
            }
    }
}

// ---------------------------------------------------------------------------
// sv: scores + softmax + v per slab.  Writes out1 fp32 AND mhb bf16.
// ---------------------------------------------------------------------------
__global__ __launch_bounds__(256, 3) void sv(
    const short* __restrict__ Xb,    // [32000][320]
    const short* __restrict__ q2,    // [slabBs][16][20][320]
    const short* __restrict__ xv,    // [32000][256]
    float*       __restrict__ out1,  // [32000][256]
    short*       __restrict__ mhb,   // [32000][256] bf16
    int bsbase)
{
    const int bs = bsbase + (blockIdx.x >> 2);
    const int hq = blockIdx.x & 3;
    const int tid = threadIdx.x, wave = tid >> 6, lane = tid & 63;
    const int lr = lane & 15, lg = lane >> 4;
    const int n = hq * 4 + wave;

    __shared__ short xs[20][328];        // stride 164 dw == 4 mod 32
    __shared__ short atw[4][32][34];     // per-wave attn scratch

    for (int i = tid; i < 2176; i += 256) reinterpret_cast<int*>(atw)[i] = 0;
    for (int idx = tid; idx < 800; idx += 256) {
        int l = idx / 40, c8 = idx % 40;
        *reinterpret_cast<bf16x8*>(&xs[l][c8 * 8]) =
            *reinterpret_cast<const bf16x8*>(Xb + ((size_t)bs * 20 + l) * 320 + c8 * 8);
    }
    __syncthreads();

    const short* qb = q2 + ((size_t)((bs - bsbase) * 16 + n) * 20) * 320;
    int l1 = 16 + lr; if (l1 > 19) l1 = 19;

    f32x4 s[2][2] = {};
    #pragma unroll
    for (int ks = 0; ks < 10; ++ks) {
        const int ko = ks * 32 + lg * 8;
        bf16x8 a0 = *reinterpret_cast<const bf16x8*>(qb + (size_t)lr * 320 + ko);
        bf16x8 a1 = *reinterpret_cast<const bf16x8*>(qb + (size_t)l1 * 320 + ko);
        bf16x8 b0 = *reinterpret_cast<const bf16x8*>(&xs[lr][ko]);
        bf16x8 b1 = *reinterpret_cast<const bf16x8*>(&xs[l1][ko]);
        s[0][0] = __builtin_amdgcn_mfma_f32_16x16x32_bf16(a0, b0, s[0][0], 0, 0, 0);
        s[0][1] = __builtin_amdgcn_mfma_f32_16x16x32_bf16(a0, b1, s[0][1], 0, 0, 0);
        s[1][0] = __builtin_amdgcn_mfma_f32_16x16x32_bf16(a1, b0, s[1][0], 0, 0, 0);
        s[1][1] = __builtin_amdgcn_mfma_f32_16x16x32_bf16(a1, b1, s[1][1], 0, 0, 0);
    }

    const float scl = 0.057735026918962584f;  // 1/sqrt(300)
    #pragma unroll
    for (int mts = 0; mts < 2; ++mts) {
        #pragma unroll
        for (int r = 0; r < 4; ++r) {
            float v0 = s[mts][0][r] * scl;
            float v1 = s[mts][1][r] * scl;
            float mx = (lr < 4) ? fmaxf(v0, v1) : v0;
            mx = fmaxf(mx, __shfl_xor(mx, 1));
            mx = fmaxf(mx, __shfl_xor(mx, 2));
            mx = fmaxf(mx, __shfl_xor(mx, 4));
            mx = fmaxf(mx, __shfl_xor(mx, 8));
            float e0 = __expf(v0 - mx);
            float e1 = (lr < 4) ? __expf(v1 - mx) : 0.f;
            float sm = e0 + e1;
            sm += __shfl_xor(sm, 1);
            sm += __shfl_xor(sm, 2);
            sm += __shfl_xor(sm, 4);
            sm += __shfl_xor(sm, 8);
            const float inv = 1.f / sm;
            const int row = mts * 16 + lg * 4 + r;
            if (row < LL) {
                atw[wave][row][lr]      = f2b(e0 * inv);
                atw[wave][row][16 + lr] = f2b(e1 * inv);   // lr>=4 writes 0
            }
        }
    }

    bf16x8 bv;
    #pragma unroll
    for (int j = 0; j < 8; ++j) {
        int m = lg * 8 + j; if (m > 19) m = 19;   // attn cols >=20 are zero
        bv[j] = xv[((size_t)bs * 20 + m) * 256 + n * 16 + lr];
    }
    bf16x8 va0 = *reinterpret_cast<const bf16x8*>(&atw[wave][lr][lg * 8]);
    bf16x8 va1 = *reinterpret_cast<const bf16x8*>(&atw[wave][16 + lr][lg * 8]);
    f32x4 z = {0.f, 0.f, 0.f, 0.f};
    f32x4 v0 = __builtin_amdgcn_mfma_f32_16x16x32_bf16(va0, bv, z, 0, 0, 0);
    f32x4 v1 = __builtin_amdgcn_mfma_f32_16x16x32_bf16(va1, bv, z, 0, 0, 0);
    #pragma unroll
    for (int r = 0; r < 4; ++r) {
        const int rowl = lg * 4 + r;
        const size_t o0 = ((size_t)bs * 20 + rowl) * 256 + n * 16 + lr;
        out1[o0] = v0[r];
        mhb[o0] = f2b(v0[r]);
        const int rowl1 = 16 + lg * 4 + r;
        if (rowl1 < LL) {
            const size_t o1 = ((size_t)bs * 20 + rowl1) * 256 + n * 16 + lr;
            out1[o1] = v1[r];
            mhb[o1] = f2b(v1[r]);
        }
    }
}

// ---------------------------------------------------------------------------
// gemm_ak: ak[32000][256] = mhb * kwb2^T.  Same m97 structure, K=256.
// ---------------------------------------------------------------------------
__global__ __launch_bounds__(256, 4) void gemm_ak(
    const short* __restrict__ mhb,   // [32000][256]
    const short* __restrict__ kwb,   // [256][256]
    short*       __restrict__ ak)    // [32000][256]
{
    const int nt0 = blockIdx.x * 128;
    const int mt0 = blockIdx.y * 128;
    const int tid = threadIdx.x, wave = tid >> 6, lane = tid & 63;
    const int lr = lane & 15, lg = lane >> 4;
    const int wm = wave & 1, wn = wave >> 1;

    __shared__ short sAB[8192];

    const int rA = tid >> 2, c = tid & 3;
    const short* aS0 = mhb + (size_t)(mt0 + rA) * 256 + c * 8;
    const short* aS1 = aS0 + (size_t)64 * 256;
    const short* bS0 = kwb + (size_t)(nt0 + rA) * 256 + c * 8;
    const short* bS1 = bS0 + (size_t)64 * 256;
    short* d0 = sAB + tid * 8;
    short* d1 = sAB + (tid + 256) * 8;
    short* d2 = sAB + (tid + 512) * 8;
    short* d3 = sAB + (tid + 768) * 8;

    f32x4 acc[4][4] = {};
    for (int ks = 0; ks < 8; ++ks) {
        __syncthreads();
        const int ko = ks * 32;
        gload16(aS0 + ko, d0);
        gload16(aS1 + ko, d1);
        gload16(bS0 + ko, d2);
        gload16(bS1 + ko, d3);
        __syncthreads();
        bf16x8 af[4], bfr[4];
        #pragma unroll
        for (int i = 0; i < 4; ++i)
            af[i] = *reinterpret_cast<const bf16x8*>(sAB + (wm * 64 + i * 16 + lr) * 32 + lg * 8);
        #pragma unroll
        for (int j = 0; j < 4; ++j)
            bfr[j] = *reinterpret_cast<const bf16x8*>(sAB + 4096 + (wn * 64 + j * 16 + lr) * 32 + lg * 8);
        #pragma unroll
        for (int i = 0; i < 4; ++i)
            #pragma unroll
            for (int j = 0; j < 4; ++j)
                acc[i][j] = __builtin_amdgcn_mfma_f32_16x16x32_bf16(af[i], bfr[j], acc[i][j], 0, 0, 0);
    }

    #pragma unroll
    for (int i = 0; i < 4; ++i)
        #pragma unroll
        for (int j = 0; j < 4; ++j)
            #pragma unroll
            for (int r = 0; r < 4; ++r)
                ak[(size_t)(mt0 + wm * 64 + i * 16 + lg * 4 + r) * 256
                   + nt0 + wn * 64 + j * 16 + lr] = f2b(acc[i][j][r]);
}

// ---------------------------------------------------------------------------
// pool_light: per bs — tanh/dot reduce, softmax, weighted sum.  No MFMA,
// no LDS tile, no atomics.  grid 1600, 256 thr.
// ---------------------------------------------------------------------------
__global__ __launch_bounds__(256) void pool_light(
    const short* __restrict__ ak,     // [32000][256] bf16
    const float* __restrict__ out1,   // mh fp32
    const float* __restrict__ keyB,   // [200]
    const float* __restrict__ query,  // [200]
    float*       __restrict__ out2)   // [NBS][256]
{
    const int bs = blockIdx.x;
    const int tid = threadIdx.x, wave = tid >> 6, lane = tid & 63;

    __shared__ float s2[LL];

    #pragma unroll
    for (int li = 0; li < 5; ++li) {
        const int l = wave * 5 + li;
        const short* ar = ak + ((size_t)bs * 20 + l) * 256;
        float acc = 0.f;
        #pragma unroll
        for (int it = 0; it < 4; ++it) {
            const int d = lane + it * 64;
            if (d < QD) {
                const float t = ftanh(b2f(ar[d]) + keyB[d]);
                acc = fmaf(query[d], t, acc);
            }
        }
        acc += __shfl_xor(acc, 32);
        acc += __shfl_xor(acc, 16);
        acc += __shfl_xor(acc, 8);
        acc += __shfl_xor(acc, 4);
        acc += __shfl_xor(acc, 2);
        acc += __shfl_xor(acc, 1);
        if (lane == 0) s2[l] = acc * 0.07071067811865475f;  // 1/sqrt(200)
    }
    __syncthreads();

    if (tid == 0) {
        float mx = -1e30f;
        #pragma unroll
        for (int l = 0; l < LL; ++l) mx = fmaxf(mx, s2[l]);
        float e[LL], sum = 0.f;
        #pragma unroll
        for (int l = 0; l < LL; ++l) { e[l] = __expf(s2[l] - mx); sum += e[l]; }
        const float inv = 1.f / sum;
        #pragma unroll
        for (int l = 0; l < LL; ++l) s2[l] = e[l] * inv;
    }
    __syncthreads();

    float o = 0.f;
    #pragma unroll
    for (int l = 0; l < LL; ++l)
        o = fmaf(s2[l], out1[((size_t)bs * 20 + l) * 256 + tid], o);
    out2[(size_t)bs * 256 + tid] = o;
}

// ===========================================================================
// FALLBACK (round-3, ~3.4 MB ws)
// ===========================================================================

#define XP 330
#define TP 42
#define AP 34

__global__ __launch_bounds__(1024) void transpose_qw(
    const float* __restrict__ qW, short* __restrict__ wqt)
{
    __shared__ float t[32][33];
    const int n = blockIdx.z;
    const int e0 = blockIdx.x * 32, f0 = blockIdx.y * 32;
    const int tx = threadIdx.x, ty = threadIdx.y;
    const int e = e0 + ty, f = f0 + tx;
    t[ty][tx] = (e < EE && f < EE) ? qW[(size_t)n * EE * EE + e * EE + f] : 0.f;
    __syncthreads();
    const int fo = f0 + ty, eo = e0 + tx;
    if (fo < 304)
        wqt[(size_t)n * 304 * 320 + fo * 320 + eo] = f2b(t[tx][ty]);
}

__global__ void conv_vw(const float* __restrict__ vW, short* __restrict__ wvt) {
    int idx = blockIdx.x * 256 + threadIdx.x;
    if (idx >= NH * VD * 320) return;
    int e = idx % 320;
    int v = (idx / 320) % VD;
    int n = idx / (320 * VD);
    wvt[idx] = (e < EE) ? f2b(vW[(size_t)n * EE * VD + e * VD + v]) : (short)0;
}

__global__ __launch_bounds__(512) void nrms_attn_mfma(
    const int*   __restrict__ news,
    const float* __restrict__ emb,
    const short* __restrict__ wqt,
    const float* __restrict__ qB,
    const short* __restrict__ wvt,
    const float* __restrict__ vB,
    float*       __restrict__ out1)
{
    const int bs   = blockIdx.x;
    const int tid  = threadIdx.x;
    const int wave = tid >> 6;
    const int lane = tid & 63;
    const int lr   = lane & 15;
    const int lg   = lane >> 4;

    __shared__ short xs[32][XP];
    __shared__ short xT[320][TP];
    __shared__ short qs[32][XP];
    __shared__ float sc[32][33];
    __shared__ short at[32][AP];

    {
        int* z = (int*)&xs[0][0];
        for (int i = tid; i < 32 * XP / 2; i += 512) z[i] = 0;
        z = (int*)&qs[0][0];
        for (int i = tid; i < 32 * XP / 2; i += 512) z[i] = 0;
        z = (int*)&xT[0][0];
        for (int i = tid; i < 320 * TP / 2; i += 512) z[i] = 0;
    }
    __syncthreads();

    for (int idx = tid; idx < LL * 75; idx += 512) {
        const int l = idx / 75, e4 = (idx % 75) * 4;
        const int row = news[bs * LL + l];
        const float4 v = *reinterpret_cast<const float4*>(emb + (size_t)row * EE + e4);
        const short b0 = f2b(v.x), b1 = f2b(v.y), b2 = f2b(v.z), b3 = f2b(v.w);
        xs[l][e4] = b0; xs[l][e4 + 1] = b1; xs[l][e4 + 2] = b2; xs[l][e4 + 3] = b3;
        xT[e4][l] = b0; xT[e4 + 1][l] = b1; xT[e4 + 2][l] = b2; xT[e4 + 3][l] = b3;
    }
    __syncthreads();

    for (int n = 0; n < NH; ++n) {
        const short* wq = wqt + (size_t)n * 304 * 320;

        for (int p = wave; p < 19; p += 8) {
            f32x4 acc0 = {0.f, 0.f, 0.f, 0.f};
            f32x4 acc1 = {0.f, 0.f, 0.f, 0.f};
            const short* a0p = &xs[lr][lg * 8];
            const short* a1p = &xs[16 + lr][lg * 8];
            const short* bp  = wq + (p * 16 + lr) * 320 + lg * 8;
            #pragma unroll
            for (int k = 0; k < 10; ++k) {
                bf16x8 b  = *reinterpret_cast<const bf16x8*>(bp + k * 32);
                bf16x8 a0 = *reinterpret_cast<const bf16x8*>(a0p + k * 32);
                bf16x8 a1 = *reinterpret_cast<const bf16x8*>(a1p + k * 32);
                acc0 = __builtin_amdgcn_mfma_f32_16x16x32_bf16(a0, b, acc0, 0, 0, 0);
                acc1 = __builtin_amdgcn_mfma_f32_16x16x32_bf16(a1, b, acc1, 0, 0, 0);
            }
            const int col = p * 16 + lr;
            const float bias = (col < EE) ? qB[n * EE + col] : 0.f;
            #pragma unroll
            for (int r = 0; r < 4; ++r) {
                qs[lg * 4 + r][col]      = f2b(acc0[r] + bias);
                qs[16 + lg * 4 + r][col] = f2b(acc1[r] + bias);
            }
        }
        __syncthreads();

        if (wave < 4) {
            const int mt = wave & 1, nt = wave >> 1;
            f32x4 acc = {0.f, 0.f, 0.f, 0.f};
            const short* ap = &qs[mt * 16 + lr][lg * 8];
            const short* bp = &xs[nt * 16 + lr][lg * 8];
            #pragma unroll
            for (int k = 0; k < 10; ++k) {
                bf16x8 a = *reinterpret_cast<const bf16x8*>(ap + k * 32);
                bf16x8 b = *reinterpret_cast<const bf16x8*>(bp + k * 32);
                acc = __builtin_amdgcn_mfma_f32_16x16x32_bf16(a, b, acc, 0, 0, 0);
            }
            #pragma unroll
            for (int r = 0; r < 4; ++r)
                sc[mt * 16 + lg * 4 + r][nt * 16 + lr] = acc[r] * 0.057735026918962584f;
        }
        __syncthreads();

        if (tid < LL) {
            float mx = -1e30f;
            #pragma unroll
            for (int m = 0; m < LL; ++m) mx = fmaxf(mx, sc[tid][m]);
            float ev[LL], sum = 0.f;
            #pragma unroll
            for (int m = 0; m < LL; ++m) { ev[m] = __expf(sc[tid][m] - mx); sum += ev[m]; }
            const float inv = 1.f / sum;
            #pragma unroll
            for (int m = 0; m < LL; ++m) at[tid][m] = f2b(ev[m] * inv);
            #pragma unroll
            for (int m = LL; m < 32; ++m) at[tid][m] = 0;
        } else if (tid < 32) {
            int* zr = (int*)&at[tid][0];
            #pragma unroll
            for (int m = 0; m < 16; ++m) zr[m] = 0;
        }
        __syncthreads();

        for (int p = wave; p < 19; p += 8) {
            bf16x8 b  = *reinterpret_cast<const bf16x8*>(&xT[p * 16 + lr][lg * 8]);
            bf16x8 a0 = *reinterpret_cast<const bf16x8*>(&at[lr][lg * 8]);
            bf16x8 a1 = *reinterpret_cast<const bf16x8*>(&at[16 + lr][lg * 8]);
            f32x4 z = {0.f, 0.f, 0.f, 0.f};
            f32x4 c0 = __builtin_amdgcn_mfma_f32_16x16x32_bf16(a0, b, z, 0, 0, 0);
            f32x4 c1 = __builtin_amdgcn_mfma_f32_16x16x32_bf16(a1, b, z, 0, 0, 0);
            const int col = p * 16 + lr;
            #pragma unroll
            for (int r = 0; r < 4; ++r) {
                qs[lg * 4 + r][col]      = f2b(c0[r]);
                qs[16 + lg * 4 + r][col] = f2b(c1[r]);
            }
        }
        __syncthreads();

        if (wave < 2) {
            const int mt = wave;
            f32x4 acc = {0.f, 0.f, 0.f, 0.f};
            const short* ap = &qs[mt * 16 + lr][lg * 8];
            const short* bp = wvt + (size_t)n * VD * 320 + lr * 320 + lg * 8;
            #pragma unroll
            for (int k = 0; k < 10; ++k) {
                bf16x8 a = *reinterpret_cast<const bf16x8*>(ap + k * 32);
                bf16x8 b = *reinterpret_cast<const bf16x8*>(bp + k * 32);
                acc = __builtin_amdgcn_mfma_f32_16x16x32_bf16(a, b, acc, 0, 0, 0);
            }
            #pragma unroll
            for (int r = 0; r < 4; ++r) {
                const int row = mt * 16 + lg * 4 + r;
                if (row < LL)
                    out1[((size_t)bs * LL + row) * HID + n * VD + lr] = acc[r] + vB[n * VD + lr];
            }
        }
        __syncthreads();
    }
}

__global__ __launch_bounds__(256) void nrms_pool_mfma(
    const float* __restrict__ out1,
    const short* __restrict__ kwb,    // [256][256] bf16 (rows >=200 zero)
    const float* __restrict__ keyB,
    const float* __restrict__ query,
    float*       __restrict__ out2)
{
    const int bs   = blockIdx.x;
    const int tid  = threadIdx.x;
    const int wave = tid >> 6;
    const int lane = tid & 63;
    const int lr   = lane & 15;
    const int lg   = lane >> 4;

    __shared__ float mh[LL][257];
    __shared__ short mhbl[32][264];
    __shared__ float s2p[32];

    for (int i = tid; i < 12 * 128; i += 256) {
        const int r = 20 + i / 128, c = (i % 128) * 2;
        *reinterpret_cast<int*>(&mhbl[r][c]) = 0;
    }
    if (tid < 32) s2p[tid] = 0.f;

    for (int idx = tid; idx < LL * 64; idx += 256) {
        const int l = idx >> 6, h4 = (idx & 63) * 4;
        const float4 v = *reinterpret_cast<const float4*>(out1 + ((size_t)bs * LL + l) * HID + h4);
        mh[l][h4] = v.x; mh[l][h4 + 1] = v.y; mh[l][h4 + 2] = v.z; mh[l][h4 + 3] = v.w;
        mhbl[l][h4] = f2b(v.x); mhbl[l][h4 + 1] = f2b(v.y);
        mhbl[l][h4 + 2] = f2b(v.z); mhbl[l][h4 + 3] = f2b(v.w);
    }
    __syncthreads();

    for (int t = wave; t < 26; t += 4) {
        const int mt = t & 1, nt = t >> 1;
        f32x4 acc = {0.f, 0.f, 0.f, 0.f};
        const short* ap = &mhbl[mt * 16 + lr][lg * 8];
        const short* bp = kwb + (nt * 16 + lr) * 256 + lg * 8;
        #pragma unroll
        for (int k = 0; k < 8; ++k) {
            bf16x8 a = *reinterpret_cast<const bf16x8*>(ap + k * 32);
            bf16x8 b = *reinterpret_cast<const bf16x8*>(bp + k * 32);
            acc = __builtin_amdgcn_mfma_f32_16x16x32_bf16(a, b, acc, 0, 0, 0);
        }
        const int d = nt * 16 + lr;
        const float qd = (d < QD) ? query[d] : 0.f;
        const float kb = (d < QD) ? keyB[d] : 0.f;
        float vals[4];
        #pragma unroll
        for (int r = 0; r < 4; ++r) vals[r] = qd * ftanh(acc[r] + kb);
        #pragma unroll
        for (int off = 1; off < 16; off <<= 1) {
            #pragma unroll
            for (int r = 0; r < 4; ++r) vals[r] += __shfl_xor(vals[r], off);
        }
        if (lr == 0) {
            #pragma unroll
            for (int r = 0; r < 4; ++r)
                atomicAdd(&s2p[mt * 16 + lg * 4 + r], vals[r]);
        }
    }
    __syncthreads();

    if (tid == 0) {
        float mx = -1e30f;
        #pragma unroll
        for (int l = 0; l < LL; ++l) mx = fmaxf(mx, s2p[l] * 0.07071067811865475f);
        float sum = 0.f;
        float e[LL];
        #pragma unroll
        for (int l = 0; l < LL; ++l) { e[l] = __expf(s2p[l] * 0.07071067811865475f - mx); sum += e[l]; }
        const float inv = 1.f / sum;
        #pragma unroll
        for (int l = 0; l < LL; ++l) s2p[l] = e[l] * inv;
    }
    __syncthreads();

    {
        const int h = tid;
        float acc = 0.f;
        #pragma unroll
        for (int l = 0; l < LL; ++l) acc = fmaf(s2p[l], mh[l][h], acc);
        out2[(size_t)bs * HID + h] = acc;
    }
}

// ===========================================================================

extern "C" void kernel_launch(void* const* d_in, const int* in_sizes, int n_in,
                              void* d_out, int out_size, void* d_ws, size_t ws_size,
                              hipStream_t stream) {
    const int*   news  = (const int*)d_in[0];
    const float* emb   = (const float*)d_in[1];
    const float* qW    = (const float*)d_in[2];
    const float* qB    = (const float*)d_in[3];
    const float* vW    = (const float*)d_in[4];
    const float* vB    = (const float*)d_in[5];
    const float* keyW  = (const float*)d_in[6];
    const float* keyB  = (const float*)d_in[7];
    const float* query = (const float*)d_in[8];

    float* out1 = (float*)d_out;            // news_embedding: 8192000 floats
    float* out2 = out1 + 8192000;           // news_repr: 409600 floats

    // base (shorts): Xb 10.24M, WqT 1.6384M, WvT 81920, xv 8.192M,
    //                kwb2 65536, mhb 8.192M, ak 8.192M
    const size_t BASE_SH = 10240000ull + 1638400 + 81920 + 8192000
                         + 65536 + 8192000 + 8192000;            // 36,601,856
    const size_t BASE_B  = BASE_SH * 2;                           // 73.2 MB
    const size_t UNIT_B  = 640ull * 5120 * 2;                     // 6.55 MB

    size_t ucap = (ws_size > BASE_B) ? (ws_size - BASE_B) / UNIT_B : 0;
    int u = (int)((ucap > 50) ? 50 : ucap);

    if (u >= 1) {
        short* Xb   = (short*)d_ws;
        short* WqT  = Xb + 10240000;
        short* WvT  = WqT + 1638400;
        short* xv   = WvT + 81920;
        short* kwb2 = xv + 8192000;
        short* mhb  = kwb2 + 65536;
        short* ak   = mhb + 8192000;
        short* q2   = ak + 8192000;                 // slab q buffer

        hipLaunchKernelGGL(build_xb_lin, dim3(10000), dim3(256), 0, stream, news, emb, Xb);
        hipLaunchKernelGGL(build_wqt_lin, dim3(10, 10, 16), dim3(32, 32), 0, stream, qW, qB, WqT);
        hipLaunchKernelGGL(build_wvt, dim3(320), dim3(256), 0, stream, vW, vB, WvT);
        hipLaunchKernelGGL(conv_kw, dim3(256), dim3(256), 0, stream, keyW, kwb2);
        hipLaunchKernelGGL(gemm_xv, dim3(2, 250), dim3(256), 0, stream, Xb, WvT, xv);

        for (int r0 = 0; r0 < 50; r0 += u) {        // 50 units of 640 rows
            const int uu = (u < 50 - r0) ? u : (50 - r0);
            hipLaunchKernelGGL(gemm_q, dim3(40, uu * 5), dim3(256), 0, stream,
                               Xb, WqT, q2, r0 * 640);
            hipLaunchKernelGGL(sv, dim3(uu * 128), dim3(256), 0, stream,
                               Xb, q2, xv, out1, mhb, r0 * 32);
        }
        hipLaunchKernelGGL(gemm_ak, dim3(2, 250), dim3(256), 0, stream, mhb, kwb2, ak);
        hipLaunchKernelGGL(pool_light, dim3(NBS), dim3(256), 0, stream,
                           ak, out1, keyB, query, out2);
    } else {
        short* wqt  = (short*)d_ws;
        short* wvt  = wqt + (size_t)NH * 304 * 320;
        short* kwb2 = wvt + (size_t)NH * VD * 320;

        hipLaunchKernelGGL(transpose_qw, dim3(10, 10, 16), dim3(32, 32), 0, stream, qW, wqt);
        hipLaunchKernelGGL(conv_vw, dim3(320), dim3(256), 0, stream, vW, wvt);
        hipLaunchKernelGGL(conv_kw, dim3(256), dim3(256), 0, stream, keyW, kwb2);
        hipLaunchKernelGGL(nrms_attn_mfma, dim3(NBS), dim3(512), 0, stream,
                           news, emb, wqt, qB, wvt, vB, out1);
        hipLaunchKernelGGL(nrms_pool_mfma, dim3(NBS), dim3(256), 0, stream,
                           out1, kwb2, keyB, query, out2);
    }
}

// Round 14
// 283.250 us; speedup vs baseline: 1.2328x; 1.1548x over previous
//
#include <hip/hip_runtime.h>
#include <math.h>

#define NBS 1600      // B*S
#define LL 20
#define EE 300
#define NH 16
#define VD 16
#define HID 256
#define QD 200

typedef short bf16x8 __attribute__((ext_vector_type(8)));
typedef float f32x4 __attribute__((ext_vector_type(4)));

__device__ __forceinline__ short f2b(float f) {
    union { float f; unsigned u; } c; c.f = f;
    unsigned r = (c.u + 0x7FFFu + ((c.u >> 16) & 1u)) >> 16;  // RNE
    return (short)r;
}

__device__ __forceinline__ float b2f(short s) {
    union { unsigned u; float f; } c; c.u = ((unsigned)(unsigned short)s) << 16;
    return c.f;
}

__device__ __forceinline__ float ftanh(float a) {
    a = fminf(fmaxf(a, -15.f), 15.f);
    float t = __expf(2.f * a);
    return (t - 1.f) / (t + 1.f);
}

__device__ __forceinline__ void gload16(const short* g, short* l) {
    __builtin_amdgcn_global_load_lds(
        (const __attribute__((address_space(1))) unsigned int*)g,
        (__attribute__((address_space(3))) unsigned int*)l, 16, 0, 0);
}

// ===========================================================================
// Build kernels
// ===========================================================================

// news/emb -> Xb bf16 [32000][320]; col300 = 1.0 (bias channel), 301..319 = 0
__global__ void build_xb_lin(const int* __restrict__ news, const float* __restrict__ emb,
                             short* __restrict__ Xb) {
    int idx = blockIdx.x * 256 + threadIdx.x;
    if (idx >= 32000 * 80) return;
    int i = idx / 80, e4 = (idx % 80) * 4;
    short4 o;
    if (e4 < 300) {
        const float4 v = *reinterpret_cast<const float4*>(emb + (size_t)news[i] * EE + e4);
        o.x = f2b(v.x); o.y = f2b(v.y); o.z = f2b(v.z); o.w = f2b(v.w);
    } else if (e4 == 300) {
        o.x = (short)0x3F80; o.y = 0; o.z = 0; o.w = 0;
    } else {
        o.x = o.y = o.z = o.w = 0;
    }
    *reinterpret_cast<short4*>(Xb + (size_t)i * 320 + e4) = o;
}

// Wq [n][e][f] -> WqT bf16 [5120 rows = n*320+f][320 cols = e], col300 = qB
__global__ __launch_bounds__(1024) void build_wqt_lin(
    const float* __restrict__ qW, const float* __restrict__ qB, short* __restrict__ WqT)
{
    __shared__ float t[32][33];
    const int n = blockIdx.z;
    const int e0 = blockIdx.x * 32, f0 = blockIdx.y * 32;
    const int tx = threadIdx.x, ty = threadIdx.y;
    const int e = e0 + ty, f = f0 + tx;
    t[ty][tx] = (e < EE && f < EE) ? qW[((size_t)n * EE + e) * EE + f] : 0.f;
    __syncthreads();
    const int fo = f0 + ty, eo = e0 + tx;
    float val;
    if (fo >= EE)      val = 0.f;
    else if (eo < EE)  val = t[tx][ty];
    else if (eo == EE) val = qB[n * EE + fo];
    else               val = 0.f;
    WqT[((size_t)n * 320 + fo) * 320 + eo] = f2b(val);
}

// Wv [n][e][v] -> WvT bf16 [256][320], col300 = vB
__global__ void build_wvt(const float* __restrict__ vW, const float* __restrict__ vB,
                          short* __restrict__ WvT) {
    int idx = blockIdx.x * 256 + threadIdx.x;
    if (idx >= 256 * 320) return;
    int c = idx / 320, e = idx % 320;
    int n = c >> 4, vd = c & 15;
    float val = (e < EE) ? vW[((size_t)n * EE + e) * VD + vd]
                         : (e == EE ? vB[n * VD + vd] : 0.f);
    WvT[idx] = f2b(val);
}

// keyW [200][256] fp32 -> bf16 kwb2 [256][256] (rows >=200 zero)
__global__ void conv_kw(const float* __restrict__ keyW, short* __restrict__ kwb) {
    int idx = blockIdx.x * 256 + threadIdx.x;
    if (idx >= 256 * 256) return;
    int d = idx >> 8;
    kwb[idx] = (d < QD) ? f2b(keyW[idx]) : (short)0;
}

// xv = Xb * WvT^T : [32000][256] bf16.  128x128 tile, 4 waves.
__global__ __launch_bounds__(256) void gemm_xv(
    const short* __restrict__ Xb, const short* __restrict__ WvT, short* __restrict__ xv)
{
    const int nt0 = blockIdx.x * 128;
    const size_t mt0 = (size_t)blockIdx.y * 128;
    const int tid = threadIdx.x, wave = tid >> 6, lane = tid & 63;
    const int lr = lane & 15, lg = lane >> 4;
    const int wm = wave & 1, wn = wave >> 1;

    __shared__ short As[128][68];
    __shared__ short Bs[128][68];
    f32x4 acc[4][4] = {};

    for (int ks = 0; ks < 5; ++ks) {
        __syncthreads();
        for (int u = 0; u < 4; ++u) {
            int idx = u * 256 + tid;
            int rr = idx >> 3, c8 = idx & 7;
            *reinterpret_cast<bf16x8*>(&As[rr][c8 * 8]) =
                *reinterpret_cast<const bf16x8*>(Xb + (mt0 + rr) * 320 + ks * 64 + c8 * 8);
            *reinterpret_cast<bf16x8*>(&Bs[rr][c8 * 8]) =
                *reinterpret_cast<const bf16x8*>(WvT + (size_t)(nt0 + rr) * 320 + ks * 64 + c8 * 8);
        }
        __syncthreads();
        #pragma unroll
        for (int kk = 0; kk < 2; ++kk) {
            bf16x8 af[4], bfv[4];
            #pragma unroll
            for (int f = 0; f < 4; ++f)
                af[f] = *reinterpret_cast<const bf16x8*>(&As[wm * 64 + f * 16 + lr][kk * 32 + lg * 8]);
            #pragma unroll
            for (int f = 0; f < 4; ++f)
                bfv[f] = *reinterpret_cast<const bf16x8*>(&Bs[wn * 64 + f * 16 + lr][kk * 32 + lg * 8]);
            #pragma unroll
            for (int i = 0; i < 4; ++i)
                #pragma unroll
                for (int j = 0; j < 4; ++j)
                    acc[i][j] = __builtin_amdgcn_mfma_f32_16x16x32_bf16(af[i], bfv[j], acc[i][j], 0, 0, 0);
        }
    }
    #pragma unroll
    for (int i = 0; i < 4; ++i)
        #pragma unroll
        for (int j = 0; j < 4; ++j)
            #pragma unroll
            for (int r = 0; r < 4; ++r)
                xv[(mt0 + wm * 64 + i * 16 + lg * 4 + r) * 256 + nt0 + wn * 64 + j * 16 + lr]
                    = f2b(acc[i][j][r]);
}

// ---------------------------------------------------------------------------
// qsv: fused q-GEMM + scores + softmax + v.  One block per (4 bs, head).
// grid (400,16), 256 thr, 4 waves.  GEMM: M=80 x N=320(full head) x K=320,
// BK=32, glds(16B) coalesced staging (A 80x32 @0, B 320x32 @2560 shorts,
// 25.6 KB), wave-tile 80x80 (5x5 acc).  Epilogue: acc->qs[80][324] (aliases
// staging), per-wave(=bs) scores vs bulk-prefetched X frags, in-reg softmax,
// v-MFMA with prefetched xv.  LDS 60.5 KB -> 2 blocks/CU.  No q traffic.
// ---------------------------------------------------------------------------
__global__ __launch_bounds__(256, 2) void qsv(
    const short* __restrict__ Xb,    // [32000][320]
    const short* __restrict__ WqT,   // [5120][320]
    const short* __restrict__ xv,    // [32000][256]
    float*       __restrict__ out1,  // [32000][256]
    short*       __restrict__ mhb)   // [32000][256] bf16
{
    const int g = blockIdx.x;        // 4-bs group
    const int n = blockIdx.y;        // head
    const int tid = threadIdx.x, wave = tid >> 6, lane = tid & 63;
    const int lr = lane & 15, lg = lane >> 4;
    const size_t row0 = (size_t)g * 80;

    // [0,12800): staging (A [80][32] @0, B [320][32] @2560)
    // [0,25920): qs [80][324] after GEMM (aliases staging)
    // [25920,30272): atw [4][32][34] (wave-private quadrants)
    __shared__ short lds[30272];

    // each wave zeros its own atw quadrant (no barrier needed)
    {
        int* az = reinterpret_cast<int*>(lds + 25920 + wave * 1088);
        for (int i = lane; i < 544; i += 64) az[i] = 0;
    }

    // staging seg map: 1600 segs of 16B; thread handles s = k*256+tid
    const short* gp[7];
    int dsto[7];
    #pragma unroll
    for (int k = 0; k < 7; ++k) {
        const int s = k * 256 + tid;
        if (s < 320) {
            gp[k]   = Xb + (row0 + (s >> 2)) * 320 + (s & 3) * 8;
            dsto[k] = s * 8;
        } else if (s < 1600) {
            const int s2 = s - 320;
            gp[k]   = WqT + (size_t)(n * 320 + (s2 >> 2)) * 320 + (s2 & 3) * 8;
            dsto[k] = 2560 + s2 * 8;
        } else {
            gp[k] = Xb; dsto[k] = 0;   // unused (k==6, tid>=64)
        }
    }

    // prefetch xv B-frag for v-phase (wave = bs)
    const int b = wave;
    bf16x8 bv;
    #pragma unroll
    for (int j = 0; j < 8; ++j) {
        int m = lg * 8 + j; if (m > 19) m = 19;   // attn cols >=20 are zero
        bv[j] = xv[(row0 + b * 20 + m) * 256 + n * 16 + lr];
    }

    // ---- q-GEMM K-loop (m97 recipe) ----
    f32x4 acc[5][5] = {};
    for (int ks = 0; ks < 10; ++ks) {
        __syncthreads();                     // staging region free
        const int ko = ks * 32;
        #pragma unroll
        for (int k = 0; k < 6; ++k)
            gload16(gp[k] + ko, lds + dsto[k]);
        if (tid < 64)
            gload16(gp[6] + ko, lds + dsto[6]);
        __syncthreads();                     // glds drained
        bf16x8 af[5], bfr[5];
        #pragma unroll
        for (int i = 0; i < 5; ++i)
            af[i] = *reinterpret_cast<const bf16x8*>(lds + (i * 16 + lr) * 32 + lg * 8);
        #pragma unroll
        for (int j = 0; j < 5; ++j)
            bfr[j] = *reinterpret_cast<const bf16x8*>(lds + 2560 + (wave * 80 + j * 16 + lr) * 32 + lg * 8);
        #pragma unroll
        for (int i = 0; i < 5; ++i)
            #pragma unroll
            for (int j = 0; j < 5; ++j)
                acc[i][j] = __builtin_amdgcn_mfma_f32_16x16x32_bf16(af[i], bfr[j], acc[i][j], 0, 0, 0);
    }
    __syncthreads();   // staging reads done -> safe to overwrite with qs

    // ---- acc -> qs [80][324]; wave w owns cols [80w, 80w+80) ----
    #pragma unroll
    for (int i = 0; i < 5; ++i)
        #pragma unroll
        for (int j = 0; j < 5; ++j)
            #pragma unroll
            for (int r = 0; r < 4; ++r)
                lds[(i * 16 + lg * 4 + r) * 324 + wave * 80 + j * 16 + lr] = f2b(acc[i][j][r]);

    // ---- bulk-prefetch scores-phase X fragments (fly over the barrier) ----
    const int rA0 = b * 20 + lr;
    int rA1 = b * 20 + 16 + lr; if (rA1 > 79) rA1 = 79;
    bf16x8 xpre0[10], xpre1[10];
    #pragma unroll
    for (int ks = 0; ks < 10; ++ks) {
        xpre0[ks] = *reinterpret_cast<const bf16x8*>(Xb + (row0 + rA0) * 320 + ks * 32 + lg * 8);
        xpre1[ks] = *reinterpret_cast<const bf16x8*>(Xb + (row0 + rA1) * 320 + ks * 32 + lg * 8);
    }
    __syncthreads();   // qs complete

    // ---- scores + in-register softmax: wave = bs ----
    short* atw = lds + 25920 + b * 1088;   // [32][34] wave-private
    {
        f32x4 s[2][2] = {};
        #pragma unroll
        for (int ks = 0; ks < 10; ++ks) {
            const int kc = ks * 32 + lg * 8;
            bf16x8 a0 = *reinterpret_cast<const bf16x8*>(lds + rA0 * 324 + kc);
            bf16x8 a1 = *reinterpret_cast<const bf16x8*>(lds + rA1 * 324 + kc);
            s[0][0] = __builtin_amdgcn_mfma_f32_16x16x32_bf16(a0, xpre0[ks], s[0][0], 0, 0, 0);
            s[0][1] = __builtin_amdgcn_mfma_f32_16x16x32_bf16(a0, xpre1[ks], s[0][1], 0, 0, 0);
            s[1][0] = __builtin_amdgcn_mfma_f32_16x16x32_bf16(a1, xpre0[ks], s[1][0], 0, 0, 0);
            s[1][1] = __builtin_amdgcn_mfma_f32_16x16x32_bf16(a1, xpre1[ks], s[1][1], 0, 0, 0);
        }

        const float scl = 0.057735026918962584f;  // 1/sqrt(300)
        #pragma unroll
        for (int mts = 0; mts < 2; ++mts) {
            #pragma unroll
            for (int r = 0; r < 4; ++r) {
                float v0 = s[mts][0][r] * scl;
                float v1 = s[mts][1][r] * scl;
                float mx = (lr < 4) ? fmaxf(v0, v1) : v0;
                mx = fmaxf(mx, __shfl_xor(mx, 1));
                mx = fmaxf(mx, __shfl_xor(mx, 2));
                mx = fmaxf(mx, __shfl_xor(mx, 4));
                mx = fmaxf(mx, __shfl_xor(mx, 8));
                float e0 = __expf(v0 - mx);
                float e1 = (lr < 4) ? __expf(v1 - mx) : 0.f;
                float sm = e0 + e1;
                sm += __shfl_xor(sm, 1);
                sm += __shfl_xor(sm, 2);
                sm += __shfl_xor(sm, 4);
                sm += __shfl_xor(sm, 8);
                const float inv = 1.f / sm;
                const int row = mts * 16 + lg * 4 + r;
                if (row < LL) {
                    atw[row * 34 + lr]      = f2b(e0 * inv);
                    atw[row * 34 + 16 + lr] = f2b(e1 * inv);   // lr>=4 writes 0
                }
            }
        }
    }
    // wave-private atw: ds-write -> ds-read ordering via lgkmcnt (proven r11/r13)

    // ---- v = attn * xv ----
    bf16x8 va0 = *reinterpret_cast<const bf16x8*>(atw + lr * 34 + lg * 8);
    bf16x8 va1 = *reinterpret_cast<const bf16x8*>(atw + (16 + lr) * 34 + lg * 8);
    f32x4 z = {0.f, 0.f, 0.f, 0.f};
    f32x4 v0 = __builtin_amdgcn_mfma_f32_16x16x32_bf16(va0, bv, z, 0, 0, 0);
    f32x4 v1 = __builtin_amdgcn_mfma_f32_16x16x32_bf16(va1, bv, z, 0, 0, 0);
    #pragma unroll
    for (int r = 0; r < 4; ++r) {
        const int rowl = lg * 4 + r;
        const size_t o0 = (row0 + b * 20 + rowl) * 256 + n * 16 + lr;
        out1[o0] = v0[r];
        mhb[o0] = f2b(v0[r]);
        const int rowl1 = 16 + lg * 4 + r;
        if (rowl1 < LL) {
            const size_t o1 = (row0 + b * 20 + rowl1) * 256 + n * 16 + lr;
            out1[o1] = v1[r];
            mhb[o1] = f2b(v1[r]);
        }
    }
}

// ---------------------------------------------------------------------------
// gemm_ak: ak[32000][256] = mhb * kwb2^T.  m97 structure, K=256.
// ---------------------------------------------------------------------------
__global__ __launch_bounds__(256, 4) void gemm_ak(
    const short* __restrict__ mhb,   // [32000][256]
    const short* __restrict__ kwb,   // [256][256]
    short*       __restrict__ ak)    // [32000][256]
{
    const int nt0 = blockIdx.x * 128;
    const int mt0 = blockIdx.y * 128;
    const int tid = threadIdx.x, wave = tid >> 6, lane = tid & 63;
    const int lr = lane & 15, lg = lane >> 4;
    const int wm = wave & 1, wn = wave >> 1;

    __shared__ short sAB[8192];

    const int rA = tid >> 2, c = tid & 3;
    const short* aS0 = mhb + (size_t)(mt0 + rA) * 256 + c * 8;
    const short* aS1 = aS0 + (size_t)64 * 256;
    const short* bS0 = kwb + (size_t)(nt0 + rA) * 256 + c * 8;
    const short* bS1 = bS0 + (size_t)64 * 256;
    short* d0 = sAB + tid * 8;
    short* d1 = sAB + (tid + 256) * 8;
    short* d2 = sAB + (tid + 512) * 8;
    short* d3 = sAB + (tid + 768) * 8;

    f32x4 acc[4][4] = {};
    for (int ks = 0; ks < 8; ++ks) {
        __syncthreads();
        const int ko = ks * 32;
        gload16(aS0 + ko, d0);
        gload16(aS1 + ko, d1);
        gload16(bS0 + ko, d2);
        gload16(bS1 + ko, d3);
        __syncthreads();
        bf16x8 af[4], bfr[4];
        #pragma unroll
        for (int i = 0; i < 4; ++i)
            af[i] = *reinterpret_cast<const bf16x8*>(sAB + (wm * 64 + i * 16 + lr) * 32 + lg * 8);
        #pragma unroll
        for (int j = 0; j < 4; ++j)
            bfr[j] = *reinterpret_cast<const bf16x8*>(sAB + 4096 + (wn * 64 + j * 16 + lr) * 32 + lg * 8);
        #pragma unroll
        for (int i = 0; i < 4; ++i)
            #pragma unroll
            for (int j = 0; j < 4; ++j)
                acc[i][j] = __builtin_amdgcn_mfma_f32_16x16x32_bf16(af[i], bfr[j], acc[i][j], 0, 0, 0);
    }

    #pragma unroll
    for (int i = 0; i < 4; ++i)
        #pragma unroll
        for (int j = 0; j < 4; ++j)
            #pragma unroll
            for (int r = 0; r < 4; ++r)
                ak[(size_t)(mt0 + wm * 64 + i * 16 + lg * 4 + r) * 256
                   + nt0 + wn * 64 + j * 16 + lr] = f2b(acc[i][j][r]);
}

// ---------------------------------------------------------------------------
// pool_light: per bs — tanh/dot reduce, softmax, weighted sum.
// ---------------------------------------------------------------------------
__global__ __launch_bounds__(256) void pool_light(
    const short* __restrict__ ak,     // [32000][256] bf16
    const float* __restrict__ out1,   // mh fp32
    const float* __restrict__ keyB,   // [200]
    const float* __restrict__ query,  // [200]
    float*       __restrict__ out2)   // [NBS][256]
{
    const int bs = blockIdx.x;
    const int tid = threadIdx.x, wave = tid >> 6, lane = tid & 63;

    __shared__ float s2[LL];

    #pragma unroll
    for (int li = 0; li < 5; ++li) {
        const int l = wave * 5 + li;
        const short* ar = ak + ((size_t)bs * 20 + l) * 256;
        float acc = 0.f;
        #pragma unroll
        for (int it = 0; it < 4; ++it) {
            const int d = lane + it * 64;
            if (d < QD) {
                const float t = ftanh(b2f(ar[d]) + keyB[d]);
                acc = fmaf(query[d], t, acc);
            }
        }
        acc += __shfl_xor(acc, 32);
        acc += __shfl_xor(acc, 16);
        acc += __shfl_xor(acc, 8);
        acc += __shfl_xor(acc, 4);
        acc += __shfl_xor(acc, 2);
        acc += __shfl_xor(acc, 1);
        if (lane == 0) s2[l] = acc * 0.07071067811865475f;  // 1/sqrt(200)
    }
    __syncthreads();

    if (tid == 0) {
        float mx = -1e30f;
        #pragma unroll
        for (int l = 0; l < LL; ++l) mx = fmaxf(mx, s2[l]);
        float e[LL], sum = 0.f;
        #pragma unroll
        for (int l = 0; l < LL; ++l) { e[l] = __expf(s2[l] - mx); sum += e[l]; }
        const float inv = 1.f / sum;
        #pragma unroll
        for (int l = 0; l < LL; ++l) s2[l] = e[l] * inv;
    }
    __syncthreads();

    float o = 0.f;
    #pragma unroll
    for (int l = 0; l < LL; ++l)
        o = fmaf(s2[l], out1[((size_t)bs * 20 + l) * 256 + tid], o);
    out2[(size_t)bs * 256 + tid] = o;
}

// ===========================================================================
// FALLBACK (round-3, ~3.4 MB ws)
// ===========================================================================

#define XP 330
#define TP 42
#define AP 34

__global__ __launch_bounds__(1024) void transpose_qw(
    const float* __restrict__ qW, short* __restrict__ wqt)
{
    __shared__ float t[32][33];
    const int n = blockIdx.z;
    const int e0 = blockIdx.x * 32, f0 = blockIdx.y * 32;
    const int tx = threadIdx.x, ty = threadIdx.y;
    const int e = e0 + ty, f = f0 + tx;
    t[ty][tx] = (e < EE && f < EE) ? qW[(size_t)n * EE * EE + e * EE + f] : 0.f;
    __syncthreads();
    const int fo = f0 + ty, eo = e0 + tx;
    if (fo < 304)
        wqt[(size_t)n * 304 * 320 + fo * 320 + eo] = f2b(t[tx][ty]);
}

__global__ void conv_vw(const float* __restrict__ vW, short* __restrict__ wvt) {
    int idx = blockIdx.x * 256 + threadIdx.x;
    if (idx >= NH * VD * 320) return;
    int e = idx % 320;
    int v = (idx / 320) % VD;
    int n = idx / (320 * VD);
    wvt[idx] = (e < EE) ? f2b(vW[(size_t)n * EE * VD + e * VD + v]) : (short)0;
}

__global__ __launch_bounds__(512) void nrms_attn_mfma(
    const int*   __restrict__ news,
    const float* __restrict__ emb,
    const short* __restrict__ wqt,
    const float* __restrict__ qB,
    const short* __restrict__ wvt,
    const float* __restrict__ vB,
    float*       __restrict__ out1)
{
    const int bs   = blockIdx.x;
    const int tid  = threadIdx.x;
    const int wave = tid >> 6;
    const int lane = tid & 63;
    const int lr   = lane & 15;
    const int lg   = lane >> 4;

    __shared__ short xs[32][XP];
    __shared__ short xT[320][TP];
    __shared__ short qs[32][XP];
    __shared__ float sc[32][33];
    __shared__ short at[32][AP];

    {
        int* z = (int*)&xs[0][0];
        for (int i = tid; i < 32 * XP / 2; i += 512) z[i] = 0;
        z = (int*)&qs[0][0];
        for (int i = tid; i < 32 * XP / 2; i += 512) z[i] = 0;
        z = (int*)&xT[0][0];
        for (int i = tid; i < 320 * TP / 2; i += 512) z[i] = 0;
    }
    __syncthreads();

    for (int idx = tid; idx < LL * 75; idx += 512) {
        const int l = idx / 75, e4 = (idx % 75) * 4;
        const int row = news[bs * LL + l];
        const float4 v = *reinterpret_cast<const float4*>(emb + (size_t)row * EE + e4);
        const short b0 = f2b(v.x), b1 = f2b(v.y), b2 = f2b(v.z), b3 = f2b(v.w);
        xs[l][e4] = b0; xs[l][e4 + 1] = b1; xs[l][e4 + 2] = b2; xs[l][e4 + 3] = b3;
        xT[e4][l] = b0; xT[e4 + 1][l] = b1; xT[e4 + 2][l] = b2; xT[e4 + 3][l] = b3;
    }
    __syncthreads();

    for (int n = 0; n < NH; ++n) {
        const short* wq = wqt + (size_t)n * 304 * 320;

        for (int p = wave; p < 19; p += 8) {
            f32x4 acc0 = {0.f, 0.f, 0.f, 0.f};
            f32x4 acc1 = {0.f, 0.f, 0.f, 0.f};
            const short* a0p = &xs[lr][lg * 8];
            const short* a1p = &xs[16 + lr][lg * 8];
            const short* bp  = wq + (p * 16 + lr) * 320 + lg * 8;
            #pragma unroll
            for (int k = 0; k < 10; ++k) {
                bf16x8 b  = *reinterpret_cast<const bf16x8*>(bp + k * 32);
                bf16x8 a0 = *reinterpret_cast<const bf16x8*>(a0p + k * 32);
                bf16x8 a1 = *reinterpret_cast<const bf16x8*>(a1p + k * 32);
                acc0 = __builtin_amdgcn_mfma_f32_16x16x32_bf16(a0, b, acc0, 0, 0, 0);
                acc1 = __builtin_amdgcn_mfma_f32_16x16x32_bf16(a1, b, acc1, 0, 0, 0);
            }
            const int col = p * 16 + lr;
            const float bias = (col < EE) ? qB[n * EE + col] : 0.f;
            #pragma unroll
            for (int r = 0; r < 4; ++r) {
                qs[lg * 4 + r][col]      = f2b(acc0[r] + bias);
                qs[16 + lg * 4 + r][col] = f2b(acc1[r] + bias);
            }
        }
        __syncthreads();

        if (wave < 4) {
            const int mt = wave & 1, nt = wave >> 1;
            f32x4 acc = {0.f, 0.f, 0.f, 0.f};
            const short* ap = &qs[mt * 16 + lr][lg * 8];
            const short* bp = &xs[nt * 16 + lr][lg * 8];
            #pragma unroll
            for (int k = 0; k < 10; ++k) {
                bf16x8 a = *reinterpret_cast<const bf16x8*>(ap + k * 32);
                bf16x8 b = *reinterpret_cast<const bf16x8*>(bp + k * 32);
                acc = __builtin_amdgcn_mfma_f32_16x16x32_bf16(a, b, acc, 0, 0, 0);
            }
            #pragma unroll
            for (int r = 0; r < 4; ++r)
                sc[mt * 16 + lg * 4 + r][nt * 16 + lr] = acc[r] * 0.057735026918962584f;
        }
        __syncthreads();

        if (tid < LL) {
            float mx = -1e30f;
            #pragma unroll
            for (int m = 0; m < LL; ++m) mx = fmaxf(mx, sc[tid][m]);
            float ev[LL], sum = 0.f;
            #pragma unroll
            for (int m = 0; m < LL; ++m) { ev[m] = __expf(sc[tid][m] - mx); sum += ev[m]; }
            const float inv = 1.f / sum;
            #pragma unroll
            for (int m = 0; m < LL; ++m) at[tid][m] = f2b(ev[m] * inv);
            #pragma unroll
            for (int m = LL; m < 32; ++m) at[tid][m] = 0;
        } else if (tid < 32) {
            int* zr = (int*)&at[tid][0];
            #pragma unroll
            for (int m = 0; m < 16; ++m) zr[m] = 0;
        }
        __syncthreads();

        for (int p = wave; p < 19; p += 8) {
            bf16x8 b  = *reinterpret_cast<const bf16x8*>(&xT[p * 16 + lr][lg * 8]);
            bf16x8 a0 = *reinterpret_cast<const bf16x8*>(&at[lr][lg * 8]);
            bf16x8 a1 = *reinterpret_cast<const bf16x8*>(&at[16 + lr][lg * 8]);
            f32x4 z = {0.f, 0.f, 0.f, 0.f};
            f32x4 c0 = __builtin_amdgcn_mfma_f32_16x16x32_bf16(a0, b, z, 0, 0, 0);
            f32x4 c1 = __builtin_amdgcn_mfma_f32_16x16x32_bf16(a1, b, z, 0, 0, 0);
            const int col = p * 16 + lr;
            #pragma unroll
            for (int r = 0; r < 4; ++r) {
                qs[lg * 4 + r][col]      = f2b(c0[r]);
                qs[16 + lg * 4 + r][col] = f2b(c1[r]);
            }
        }
        __syncthreads();

        if (wave < 2) {
            const int mt = wave;
            f32x4 acc = {0.f, 0.f, 0.f, 0.f};
            const short* ap = &qs[mt * 16 + lr][lg * 8];
            const short* bp = wvt + (size_t)n * VD * 320 + lr * 320 + lg * 8;
            #pragma unroll
            for (int k = 0; k < 10; ++k) {
                bf16x8 a = *reinterpret_cast<const bf16x8*>(ap + k * 32);
                bf16x8 b = *reinterpret_cast<const bf16x8*>(bp + k * 32);
                acc = __builtin_amdgcn_mfma_f32_16x16x32_bf16(a, b, acc, 0, 0, 0);
            }
            #pragma unroll
            for (int r = 0; r < 4; ++r) {
                const int row = mt * 16 + lg * 4 + r;
                if (row < LL)
                    out1[((size_t)bs * LL + row) * HID + n * VD + lr] = acc[r] + vB[n * VD + lr];
            }
        }
        __syncthreads();
    }
}

__global__ __launch_bounds__(256) void nrms_pool_mfma(
    const float* __restrict__ out1,
    const short* __restrict__ kwb,    // [256][256] bf16 (rows >=200 zero)
    const float* __restrict__ keyB,
    const float* __restrict__ query,
    float*       __restrict__ out2)
{
    const int bs   = blockIdx.x;
    const int tid  = threadIdx.x;
    const int wave = tid >> 6;
    const int lane = tid & 63;
    const int lr   = lane & 15;
    const int lg   = lane >> 4;

    __shared__ float mh[LL][257];
    __shared__ short mhbl[32][264];
    __shared__ float s2p[32];

    for (int i = tid; i < 12 * 128; i += 256) {
        const int r = 20 + i / 128, c = (i % 128) * 2;
        *reinterpret_cast<int*>(&mhbl[r][c]) = 0;
    }
    if (tid < 32) s2p[tid] = 0.f;

    for (int idx = tid; idx < LL * 64; idx += 256) {
        const int l = idx >> 6, h4 = (idx & 63) * 4;
        const float4 v = *reinterpret_cast<const float4*>(out1 + ((size_t)bs * LL + l) * HID + h4);
        mh[l][h4] = v.x; mh[l][h4 + 1] = v.y; mh[l][h4 + 2] = v.z; mh[l][h4 + 3] = v.w;
        mhbl[l][h4] = f2b(v.x); mhbl[l][h4 + 1] = f2b(v.y);
        mhbl[l][h4 + 2] = f2b(v.z); mhbl[l][h4 + 3] = f2b(v.w);
    }
    __syncthreads();

    for (int t = wave; t < 26; t += 4) {
        const int mt = t & 1, nt = t >> 1;
        f32x4 acc = {0.f, 0.f, 0.f, 0.f};
        const short* ap = &mhbl[mt * 16 + lr][lg * 8];
        const short* bp = kwb + (nt * 16 + lr) * 256 + lg * 8;
        #pragma unroll
        for (int k = 0; k < 8; ++k) {
            bf16x8 a = *reinterpret_cast<const bf16x8*>(ap + k * 32);
            bf16x8 b = *reinterpret_cast<const bf16x8*>(bp + k * 32);
            acc = __builtin_amdgcn_mfma_f32_16x16x32_bf16(a, b, acc, 0, 0, 0);
        }
        const int d = nt * 16 + lr;
        const float qd = (d < QD) ? query[d] : 0.f;
        const float kb = (d < QD) ? keyB[d] : 0.f;
        float vals[4];
        #pragma unroll
        for (int r = 0; r < 4; ++r) vals[r] = qd * ftanh(acc[r] + kb);
        #pragma unroll
        for (int off = 1; off < 16; off <<= 1) {
            #pragma unroll
            for (int r = 0; r < 4; ++r) vals[r] += __shfl_xor(vals[r], off);
        }
        if (lr == 0) {
            #pragma unroll
            for (int r = 0; r < 4; ++r)
                atomicAdd(&s2p[mt * 16 + lg * 4 + r], vals[r]);
        }
    }
    __syncthreads();

    if (tid == 0) {
        float mx = -1e30f;
        #pragma unroll
        for (int l = 0; l < LL; ++l) mx = fmaxf(mx, s2p[l] * 0.07071067811865475f);
        float sum = 0.f;
        float e[LL];
        #pragma unroll
        for (int l = 0; l < LL; ++l) { e[l] = __expf(s2p[l] * 0.07071067811865475f - mx); sum += e[l]; }
        const float inv = 1.f / sum;
        #pragma unroll
        for (int l = 0; l < LL; ++l) s2p[l] = e[l] * inv;
    }
    __syncthreads();

    {
        const int h = tid;
        float acc = 0.f;
        #pragma unroll
        for (int l = 0; l < LL; ++l) acc = fmaf(s2p[l], mh[l][h], acc);
        out2[(size_t)bs * HID + h] = acc;
    }
}

// ===========================================================================

extern "C" void kernel_launch(void* const* d_in, const int* in_sizes, int n_in,
                              void* d_out, int out_size, void* d_ws, size_t ws_size,
                              hipStream_t stream) {
    const int*   news  = (const int*)d_in[0];
    const float* emb   = (const float*)d_in[1];
    const float* qW    = (const float*)d_in[2];
    const float* qB    = (const float*)d_in[3];
    const float* vW    = (const float*)d_in[4];
    const float* vB    = (const float*)d_in[5];
    const float* keyW  = (const float*)d_in[6];
    const float* keyB  = (const float*)d_in[7];
    const float* query = (const float*)d_in[8];

    float* out1 = (float*)d_out;            // news_embedding: 8192000 floats
    float* out2 = out1 + 8192000;           // news_repr: 409600 floats

    // base (shorts): Xb 10.24M, WqT 1.6384M, WvT 81920, xv 8.192M,
    //                kwb2 65536, mhb 8.192M, ak 8.192M  = 36,601,856 (73.2 MB)
    const size_t BASE_SH = 10240000ull + 1638400 + 81920 + 8192000
                         + 65536 + 8192000 + 8192000;
    const size_t BASE_B  = BASE_SH * 2;

    if (ws_size >= BASE_B) {
        short* Xb   = (short*)d_ws;
        short* WqT  = Xb + 10240000;
        short* WvT  = WqT + 1638400;
        short* xv   = WvT + 81920;
        short* kwb2 = xv + 8192000;
        short* mhb  = kwb2 + 65536;
        short* ak   = mhb + 8192000;

        hipLaunchKernelGGL(build_xb_lin, dim3(10000), dim3(256), 0, stream, news, emb, Xb);
        hipLaunchKernelGGL(build_wqt_lin, dim3(10, 10, 16), dim3(32, 32), 0, stream, qW, qB, WqT);
        hipLaunchKernelGGL(build_wvt, dim3(320), dim3(256), 0, stream, vW, vB, WvT);
        hipLaunchKernelGGL(conv_kw, dim3(256), dim3(256), 0, stream, keyW, kwb2);
        hipLaunchKernelGGL(gemm_xv, dim3(2, 250), dim3(256), 0, stream, Xb, WvT, xv);
        hipLaunchKernelGGL(qsv, dim3(400, 16), dim3(256), 0, stream,
                           Xb, WqT, xv, out1, mhb);
        hipLaunchKernelGGL(gemm_ak, dim3(2, 250), dim3(256), 0, stream, mhb, kwb2, ak);
        hipLaunchKernelGGL(pool_light, dim3(NBS), dim3(256), 0, stream,
                           ak, out1, keyB, query, out2);
    } else {
        short* wqt  = (short*)d_ws;
        short* wvt  = wqt + (size_t)NH * 304 * 320;
        short* kwb2 = wvt + (size_t)NH * VD * 320;

        hipLaunchKernelGGL(transpose_qw, dim3(10, 10, 16), dim3(32, 32), 0, stream, qW, wqt);
        hipLaunchKernelGGL(conv_vw, dim3(320), dim3(256), 0, stream, vW, wvt);
        hipLaunchKernelGGL(conv_kw, dim3(256), dim3(256), 0, stream, keyW, kwb2);
        hipLaunchKernelGGL(nrms_attn_mfma, dim3(NBS), dim3(512), 0, stream,
                           news, emb, wqt, qB, wvt, vB, out1);
        hipLaunchKernelGGL(nrms_pool_mfma, dim3(NBS), dim3(256), 0, stream,
                           out1, kwb2, keyB, query, out2);
    }
}